// Round 8
// baseline (353.667 us; speedup 1.0000x reference)
//
#include <hip/hip_runtime.h>
#include <hip/hip_fp16.h>
#include <math.h>
#include <stddef.h>

#define D_DIM 128
#define NUM_RBF 20
typedef unsigned short ushort_t;
typedef unsigned int uint_t;
typedef _Float16 h2v __attribute__((ext_vector_type(2)));
constexpr float PI_F = 3.14159265358979323846f;
constexpr float CUT_OFF_F = 5.0f;
constexpr float SILU_SCALE_F = 1.0f / 0.6f;

__device__ __forceinline__ uint_t pack2h(float a, float b) {
  __half2 h2 = __floats2half2_rn(a, b);
  return *reinterpret_cast<uint_t*>(&h2);
}
__device__ __forceinline__ float h2f(ushort_t u) {
  __half h = __ushort_as_half(u);
  return __half2float(h);
}
__device__ __forceinline__ float h2f_lo(uint_t u) { return h2f((ushort_t)(u & 0xffffu)); }
__device__ __forceinline__ float h2f_hi(uint_t u) { return h2f((ushort_t)(u >> 16)); }
__device__ __forceinline__ h2v u2h2(uint_t u) {
  h2v r;
  __builtin_memcpy(&r, &u, 4);
  return r;
}

#if defined(__has_builtin)
#if __has_builtin(__builtin_amdgcn_fdot2)
#define HAVE_FDOT2 1
#endif
#endif

__device__ __forceinline__ float fdot2f(h2v a, h2v b, float c) {
#ifdef HAVE_FDOT2
  return __builtin_amdgcn_fdot2(a, b, c, false);
#else
  return c + (float)a.x * (float)b.x + (float)a.y * (float)b.y;
#endif
}

// ---------------------------------------------------------------------------
// Fused node projection + merged-buffer build.
// s = scaled_silu(X @ W1 + b1) @ W2 + b2, natural column order throughout
// the GEMM (conflict-free 16B-lane-stride LDS reads). The merged [N][128][6]
// fp16 buffer {s(3d),s(3d+1),s(3d+2),v0,v1,v2} is produced by an LDS bounce:
// acc2 -> fp16 natural [32][384] in LDS -> cooperative repack + vf merge.
// LDS: smA 16KB (xs/hs) + smB 24KB (W1 32-row chunk / W2 16-row chunk /
// s-stage) = 40KB -> 4 blocks/CU.
// ---------------------------------------------------------------------------
__global__ __launch_bounds__(256) void proj_kernel(
    const float* __restrict__ X, const float* __restrict__ W1,
    const float* __restrict__ b1, const float* __restrict__ W2,
    const float* __restrict__ b2, const float* __restrict__ vf,
    uint_t* __restrict__ merged, int N) {
  __shared__ float smA[32 * 128];   // xs then hs
  __shared__ float smB[6144];       // W1 chunk (32x128) / W2 chunk (16x384) / s-stage
  float* xs = smA;
  float* hs = smA;
  float* w1s = smB;
  float* w2c = smB;

  const int t = threadIdx.x;
  const int nb = blockIdx.x * 32;

  {
    const float4* Xv = reinterpret_cast<const float4*>(X);
    float4* xsv = reinterpret_cast<float4*>(xs);
#pragma unroll
    for (int i = 0; i < 4; ++i) {
      int f4 = t + i * 256;
      int node = nb + (f4 >> 5);
      xsv[f4] = (node < N) ? Xv[(size_t)nb * 32 + f4]
                           : make_float4(0.f, 0.f, 0.f, 0.f);
    }
  }
  __syncthreads();

  const int c0 = (t & 31) * 4;   // col 0..124
  const int r0 = (t >> 5) * 4;   // row 0..28

  // ---- phase 1: h = X @ W1, W1 in 4 chunks of 32 K-rows (16KB) ----
  float acc1[4][4] = {};
  for (int kc1 = 0; kc1 < 128; kc1 += 32) {
    __syncthreads();
    {
      const float4* W1v = reinterpret_cast<const float4*>(W1);
      float4* wv = reinterpret_cast<float4*>(w1s);
#pragma unroll
      for (int i = 0; i < 4; ++i)
        wv[t + i * 256] = W1v[kc1 * 32 + t + i * 256];
    }
    __syncthreads();
    for (int k = 0; k < 32; k += 4) {
      float xa[4][4];
#pragma unroll
      for (int i = 0; i < 4; ++i) {
        float4 xt =
            *reinterpret_cast<const float4*>(&xs[(r0 + i) * 128 + kc1 + k]);
        xa[i][0] = xt.x; xa[i][1] = xt.y; xa[i][2] = xt.z; xa[i][3] = xt.w;
      }
#pragma unroll
      for (int kk = 0; kk < 4; ++kk) {
        float4 wv = *reinterpret_cast<const float4*>(&w1s[(k + kk) * 128 + c0]);
        float wa[4] = {wv.x, wv.y, wv.z, wv.w};
#pragma unroll
        for (int i = 0; i < 4; ++i)
#pragma unroll
          for (int j = 0; j < 4; ++j) acc1[i][j] += xa[i][kk] * wa[j];
      }
    }
  }
  __syncthreads();   // xs reads complete before hs overwrite

  // ---- bias + scaled silu, float4 stores (16B lane stride, no conflict) ----
  {
    float b1v[4];
#pragma unroll
    for (int j = 0; j < 4; ++j) b1v[j] = b1[c0 + j];
#pragma unroll
    for (int i = 0; i < 4; ++i) {
      float hv[4];
#pragma unroll
      for (int j = 0; j < 4; ++j) {
        float h = acc1[i][j] + b1v[j];
        hv[j] = h * SILU_SCALE_F / (1.0f + expf(-h));
      }
      *reinterpret_cast<float4*>(&hs[(r0 + i) * 128 + c0]) =
          make_float4(hv[0], hv[1], hv[2], hv[3]);
    }
  }

  // ---- phase 2: natural cols m*128+c0+j, W2 in 8 chunks of 16 K-rows ----
  float acc2[4][3][4];
#pragma unroll
  for (int m = 0; m < 3; ++m)
#pragma unroll
    for (int j = 0; j < 4; ++j) {
      float bv = b2[m * 128 + c0 + j];
#pragma unroll
      for (int i = 0; i < 4; ++i) acc2[i][m][j] = bv;
    }

  for (int kc = 0; kc < 128; kc += 16) {
    __syncthreads();
    {
      const float4* W2v = reinterpret_cast<const float4*>(W2);
      float4* wv = reinterpret_cast<float4*>(w2c);
#pragma unroll
      for (int i = 0; i < 6; ++i)
        wv[t + i * 256] = W2v[(size_t)kc * 96 + t + i * 256];
    }
    __syncthreads();
    for (int kk = 0; kk < 16; ++kk) {
      float xr[4];
#pragma unroll
      for (int i = 0; i < 4; ++i) xr[i] = hs[(r0 + i) * 128 + kc + kk];
#pragma unroll
      for (int m = 0; m < 3; ++m) {
        float4 wv = *reinterpret_cast<const float4*>(&w2c[kk * 384 + m * 128 + c0]);
        float wa[4] = {wv.x, wv.y, wv.z, wv.w};
#pragma unroll
        for (int i = 0; i < 4; ++i)
#pragma unroll
          for (int j = 0; j < 4; ++j) acc2[i][m][j] += xr[i] * wa[j];
      }
    }
  }

  // ---- epilogue: LDS bounce to fp16 natural [32][384], then merged build ---
  __syncthreads();   // last W2 chunk reads done before smB overwrite
  ushort_t* sh = reinterpret_cast<ushort_t*>(smB);
#pragma unroll
  for (int i = 0; i < 4; ++i) {
#pragma unroll
    for (int m = 0; m < 3; ++m) {
      uint2 v = make_uint2(pack2h(acc2[i][m][0], acc2[i][m][1]),
                           pack2h(acc2[i][m][2], acc2[i][m][3]));
      *reinterpret_cast<uint2*>(&sh[(r0 + i) * 384 + m * 128 + c0]) = v;
    }
  }
  __syncthreads();

#pragma unroll
  for (int k = 0; k < 16; ++k) {
    const int P = k * 256 + t;       // 0..4095
    const int ln = P >> 7;           // local node 0..31
    const int chan = P & 127;
    const int node = nb + ln;
    if (node < N) {
      const ushort_t* sp = &sh[ln * 384 + 3 * chan];
      const ushort_t sa = sp[0], sb = sp[1], sc = sp[2];
      const float* vp = vf + ((size_t)node * 128 + chan) * 3;
      const float v0 = vp[0], v1 = vp[1], v2 = vp[2];
      uint_t* mp = merged + ((size_t)node * 128 + chan) * 3;
      mp[0] = (uint_t)sa | ((uint_t)sb << 16);
      mp[1] = (uint_t)sc |
              ((uint_t)__half_as_ushort(__float2half_rn(v0)) << 16);
      mp[2] = pack2h(v1, v2);
    }
  }
}

// ---------------------------------------------------------------------------
// CSR build
// ---------------------------------------------------------------------------
__global__ void zero_kernel(int* __restrict__ p, int n) {
  int i = blockIdx.x * 256 + threadIdx.x;
  if (i < n) p[i] = 0;
}

__global__ void hist_kernel(const int* __restrict__ tgt, int* __restrict__ counts,
                            int E) {
  int e = blockIdx.x * 256 + threadIdx.x;
  if (e < E) atomicAdd(&counts[tgt[e]], 1);
}

__global__ void chunk_sum_kernel(const int* __restrict__ counts,
                                 int* __restrict__ chunk_sums, int N) {
  __shared__ int red[256];
  int b = blockIdx.x, t = threadIdx.x;
  int base = b * 1024 + t * 4;
  int s = 0;
#pragma unroll
  for (int j = 0; j < 4; ++j) s += (base + j < N) ? counts[base + j] : 0;
  red[t] = s;
  __syncthreads();
  for (int off = 128; off > 0; off >>= 1) {
    if (t < off) red[t] += red[t + off];
    __syncthreads();
  }
  if (t == 0) chunk_sums[b] = red[0];
}

__global__ void scan_chunks_kernel(int* __restrict__ chunk_sums,
                                   int* __restrict__ offsets, int nch, int N,
                                   int E) {
  int t = threadIdx.x;  // one wave; nch <= 64
  int v = (t < nch) ? chunk_sums[t] : 0;
  int orig = v;
#pragma unroll
  for (int off = 1; off < 64; off <<= 1) {
    int y = __shfl_up(v, off);
    if (t >= off) v += y;
  }
  if (t < nch) chunk_sums[t] = v - orig;
  if (t == 0) offsets[N] = E;
}

__global__ void scan_block_kernel(const int* __restrict__ counts,
                                  const int* __restrict__ chunk_off,
                                  int* __restrict__ offsets,
                                  int* __restrict__ cursor, int N) {
  __shared__ int part[256];
  int b = blockIdx.x, t = threadIdx.x;
  int base = b * 1024 + t * 4;
  int v[4];
#pragma unroll
  for (int j = 0; j < 4; ++j) v[j] = (base + j < N) ? counts[base + j] : 0;
  int local = v[0] + v[1] + v[2] + v[3];
  part[t] = local;
  __syncthreads();
  for (int off = 1; off < 256; off <<= 1) {
    int x = 0;
    if (t >= off) x = part[t - off];
    __syncthreads();
    if (t >= off) part[t] += x;
    __syncthreads();
  }
  int run = chunk_off[b] + (part[t] - local);
#pragma unroll
  for (int j = 0; j < 4; ++j) {
    if (base + j < N) {
      offsets[base + j] = run;
      cursor[base + j] = run;
      run += v[j];
    }
  }
}

// ---------------------------------------------------------------------------
// Fused edge geometry + CSR scatter. rbf packed fp16 (10 x half2, stride 12
// uints for 16B alignment), dir fp32.
// ---------------------------------------------------------------------------
__global__ void edge_geom_kernel(const float* __restrict__ pos,
                                 const int* __restrict__ src,
                                 const int* __restrict__ tgt,
                                 int* __restrict__ cursor,
                                 float4* __restrict__ dir4_s,
                                 uint_t* __restrict__ rbh_s,
                                 int* __restrict__ src_s, int E) {
  int e = blockIdx.x * 256 + threadIdx.x;
  if (e >= E) return;
  const int sn = src[e];
  const int tn = tgt[e];
  const float rx = pos[tn * 3 + 0] - pos[sn * 3 + 0];
  const float ry = pos[tn * 3 + 1] - pos[sn * 3 + 1];
  const float rz = pos[tn * 3 + 2] - pos[sn * 3 + 2];
  const float dist = sqrtf(rx * rx + ry * ry + rz * rz);
  const float inv = 1.0f / dist;

  const float ang = dist * (PI_F / CUT_OFF_F);
  float s1, c1;
  sincosf(ang, &s1, &c1);
  float sk = s1, ck = c1;
  float rb[NUM_RBF];
  rb[0] = s1 * inv;
#pragma unroll
  for (int r = 1; r < NUM_RBF; ++r) {
    float sn2 = sk * c1 + ck * s1;
    ck = ck * c1 - sk * s1;
    sk = sn2;
    rb[r] = sk * inv;
  }

  const int p = atomicAdd(&cursor[tn], 1);
  dir4_s[p] = make_float4(rx * inv, ry * inv, rz * inv, dist);
  src_s[p] = sn;
  uint_t us[10];
#pragma unroll
  for (int q = 0; q < 10; ++q) us[q] = pack2h(rb[2 * q], rb[2 * q + 1]);
  uint_t* o = rbh_s + (size_t)p * 12;
  *reinterpret_cast<uint4*>(o) = make_uint4(us[0], us[1], us[2], us[3]);
  *reinterpret_cast<uint4*>(o + 4) = make_uint4(us[4], us[5], us[6], us[7]);
  *reinterpret_cast<uint2*>(o + 8) = make_uint2(us[8], us[9]);
}

// ---------------------------------------------------------------------------
// Node gather. Single merged fp16 gather (3 uints, one base) per edge-lane,
// packed-fp16 rbf with v_dot2 filter dot, shfl-broadcast src, x2 ILP.
// ---------------------------------------------------------------------------
#define NODES_PER_BLOCK 8

__device__ __forceinline__ float cutoff_f(float x) {
  return (x < CUT_OFF_F) ? 0.5f * (1.0f + __cosf(x * (PI_F / CUT_OFF_F))) : 0.f;
}

struct EdgeData {
  float4 dir;
  uint_t rbu[10];
  uint_t su[3];
};

__device__ __forceinline__ void load_edge(int idx, int sn, int d,
                                          const uint_t* __restrict__ merged,
                                          const float4* __restrict__ dir4_s,
                                          const uint_t* __restrict__ rbh_s,
                                          EdgeData& ed) {
  ed.dir = dir4_s[idx];
  const uint_t* o = rbh_s + (size_t)idx * 12;
  uint4 u0 = *reinterpret_cast<const uint4*>(o);
  uint4 u1 = *reinterpret_cast<const uint4*>(o + 4);
  uint2 u2 = *reinterpret_cast<const uint2*>(o + 8);
  ed.rbu[0] = u0.x; ed.rbu[1] = u0.y; ed.rbu[2] = u0.z; ed.rbu[3] = u0.w;
  ed.rbu[4] = u1.x; ed.rbu[5] = u1.y; ed.rbu[6] = u1.z; ed.rbu[7] = u1.w;
  ed.rbu[8] = u2.x; ed.rbu[9] = u2.y;
  const uint_t* mp = merged + ((size_t)sn * 128 + d) * 3;
  ed.su[0] = mp[0]; ed.su[1] = mp[1]; ed.su[2] = mp[2];
}

__global__ __launch_bounds__(128) void node_kernel(
    const uint_t* __restrict__ merged, const float4* __restrict__ dir4_s,
    const uint_t* __restrict__ rbh_s, const int* __restrict__ src_s,
    const int* __restrict__ offsets, const float* __restrict__ Wr,
    const float* __restrict__ br, float* __restrict__ out, int N, int E) {
  const int d = threadIdx.x;
  const int lane = d & 63;

  h2v wr0h[10], wr1h[10], wr2h[10];
#pragma unroll
  for (int q = 0; q < 10; ++q) {
    h2v w;
    w.x = (_Float16)Wr[(2 * q) * 384 + 3 * d + 0];
    w.y = (_Float16)Wr[(2 * q + 1) * 384 + 3 * d + 0];
    wr0h[q] = w;
    w.x = (_Float16)Wr[(2 * q) * 384 + 3 * d + 1];
    w.y = (_Float16)Wr[(2 * q + 1) * 384 + 3 * d + 1];
    wr1h[q] = w;
    w.x = (_Float16)Wr[(2 * q) * 384 + 3 * d + 2];
    w.y = (_Float16)Wr[(2 * q + 1) * 384 + 3 * d + 2];
    wr2h[q] = w;
  }
  const float br0 = br[3 * d + 0];
  const float br1 = br[3 * d + 1];
  const float br2 = br[3 * d + 2];

  for (int nn = 0; nn < NODES_PER_BLOCK; ++nn) {
    const int n = blockIdx.x * NODES_PER_BLOCK + nn;
    if (n >= N) break;

    const int start = offsets[n];
    const int end = offsets[n + 1];

    float accs = 0.f, av0 = 0.f, av1 = 0.f, av2 = 0.f;

    for (int base = start; base < end; base += 64) {
      const int m = min(64, end - base);
      int ld = base + lane;
      if (ld >= E) ld = E - 1;
      const int sn_l = src_s[ld];

      int i = 0;
      for (; i + 2 <= m; i += 2) {
        const int sn0 = __shfl(sn_l, i);
        const int sn1 = __shfl(sn_l, i + 1);
        EdgeData e0, e1;
        load_edge(base + i, sn0, d, merged, dir4_s, rbh_s, e0);
        load_edge(base + i + 1, sn1, d, merged, dir4_s, rbh_s, e1);

#pragma unroll
        for (int u = 0; u < 2; ++u) {
          const EdgeData& ed = (u == 0) ? e0 : e1;
          float f0 = br0, f1 = br1, f2 = br2;
#pragma unroll
          for (int q = 0; q < 10; ++q) {
            h2v r = u2h2(ed.rbu[q]);
            f0 = fdot2f(r, wr0h[q], f0);
            f1 = fdot2f(r, wr1h[q], f1);
            f2 = fdot2f(r, wr2h[q], f2);
          }
          f0 = cutoff_f(f0);
          f1 = cutoff_f(f1);
          f2 = cutoff_f(f2);
          const float m0 = h2f_lo(ed.su[0]) * f0;
          const float m1 = h2f_hi(ed.su[0]) * f1;
          const float m2 = h2f_lo(ed.su[1]) * f2;
          accs += m0;
          av0 += m2 * ed.dir.x + m1 * h2f_hi(ed.su[1]);
          av1 += m2 * ed.dir.y + m1 * h2f_lo(ed.su[2]);
          av2 += m2 * ed.dir.z + m1 * h2f_hi(ed.su[2]);
        }
      }
      if (i < m) {
        const int sn0 = __shfl(sn_l, i);
        EdgeData e0;
        load_edge(base + i, sn0, d, merged, dir4_s, rbh_s, e0);
        float f0 = br0, f1 = br1, f2 = br2;
#pragma unroll
        for (int q = 0; q < 10; ++q) {
          h2v r = u2h2(e0.rbu[q]);
          f0 = fdot2f(r, wr0h[q], f0);
          f1 = fdot2f(r, wr1h[q], f1);
          f2 = fdot2f(r, wr2h[q], f2);
        }
        f0 = cutoff_f(f0);
        f1 = cutoff_f(f1);
        f2 = cutoff_f(f2);
        const float m0 = h2f_lo(e0.su[0]) * f0;
        const float m1 = h2f_hi(e0.su[0]) * f1;
        const float m2 = h2f_lo(e0.su[1]) * f2;
        accs += m0;
        av0 += m2 * e0.dir.x + m1 * h2f_hi(e0.su[1]);
        av1 += m2 * e0.dir.y + m1 * h2f_lo(e0.su[2]);
        av2 += m2 * e0.dir.z + m1 * h2f_hi(e0.su[2]);
      }
    }

    out[(size_t)n * 384 + 3 * d + 0] = av0;
    out[(size_t)n * 384 + 3 * d + 1] = av1;
    out[(size_t)n * 384 + 3 * d + 2] = av2;
    out[(size_t)N * 384 + (size_t)n * 128 + d] = accs;
  }
}

// ---------------------------------------------------------------------------
extern "C" void kernel_launch(void* const* d_in, const int* in_sizes, int n_in,
                              void* d_out, int out_size, void* d_ws,
                              size_t ws_size, hipStream_t stream) {
  const float* vf  = (const float*)d_in[0];   // [N,128,3]
  const float* X   = (const float*)d_in[1];   // [N,128]
  const float* pos = (const float*)d_in[2];   // [N,3]
  const int* ei    = (const int*)d_in[3];     // [2,E]
  const float* W1  = (const float*)d_in[4];
  const float* b1  = (const float*)d_in[5];
  const float* W2  = (const float*)d_in[6];
  const float* b2  = (const float*)d_in[7];
  const float* Wr  = (const float*)d_in[8];
  const float* br  = (const float*)d_in[9];

  const int N = in_sizes[1] / D_DIM;
  const int E = in_sizes[3] / 2;
  const int* srcI = ei;
  const int* tgtI = ei + E;
  float* out = (float*)d_out;

  // workspace layout (16B-aligned chunks first)
  char* w = (char*)d_ws;
  float4* dir4_s = (float4*)w;  w += (size_t)E * sizeof(float4);
  uint_t* rbh_s  = (uint_t*)w;  w += (size_t)E * 12 * sizeof(uint_t);
  uint_t* merged = (uint_t*)w;  w += (size_t)N * 128 * 3 * sizeof(uint_t);
  int* src_s     = (int*)w;     w += (size_t)E * sizeof(int);
  int* counts    = (int*)w;     w += (size_t)N * sizeof(int);
  int* offsets   = (int*)w;     w += (size_t)(N + 1) * sizeof(int);
  int* cursor    = (int*)w;     w += (size_t)N * sizeof(int);
  int* chunks    = (int*)w;     w += 64 * sizeof(int);

  const int nch = (N + 1023) / 1024;  // 49 for N=50000

  zero_kernel<<<(N + 255) / 256, 256, 0, stream>>>(counts, N);
  proj_kernel<<<(N + 31) / 32, 256, 0, stream>>>(X, W1, b1, W2, b2, vf, merged,
                                                 N);
  hist_kernel<<<(E + 255) / 256, 256, 0, stream>>>(tgtI, counts, E);
  chunk_sum_kernel<<<nch, 256, 0, stream>>>(counts, chunks, N);
  scan_chunks_kernel<<<1, 64, 0, stream>>>(chunks, offsets, nch, N, E);
  scan_block_kernel<<<nch, 256, 0, stream>>>(counts, chunks, offsets, cursor, N);
  edge_geom_kernel<<<(E + 255) / 256, 256, 0, stream>>>(pos, srcI, tgtI, cursor,
                                                        dir4_s, rbh_s, src_s, E);
  node_kernel<<<(N + NODES_PER_BLOCK - 1) / NODES_PER_BLOCK, 128, 0, stream>>>(
      merged, dir4_s, rbh_s, src_s, offsets, Wr, br, out, N, E);
}

// Round 9
// 311.658 us; speedup vs baseline: 1.1348x; 1.1348x over previous
//
#include <hip/hip_runtime.h>
#include <hip/hip_fp16.h>
#include <math.h>
#include <stddef.h>

#define D_DIM 128
#define NUM_RBF 20
typedef unsigned short ushort_t;
typedef unsigned int uint_t;
typedef _Float16 h2v __attribute__((ext_vector_type(2)));
typedef _Float16 half8_t __attribute__((ext_vector_type(8)));
typedef float float4_t __attribute__((ext_vector_type(4)));
constexpr float PI_F = 3.14159265358979323846f;
constexpr float CUT_OFF_F = 5.0f;
constexpr float SILU_SCALE_F = 1.0f / 0.6f;

__device__ __forceinline__ uint_t pack2h(float a, float b) {
  __half2 h2 = __floats2half2_rn(a, b);
  return *reinterpret_cast<uint_t*>(&h2);
}
__device__ __forceinline__ float h2f(ushort_t u) {
  __half h = __ushort_as_half(u);
  return __half2float(h);
}
__device__ __forceinline__ h2v u2h2(uint_t u) {
  h2v r;
  __builtin_memcpy(&r, &u, 4);
  return r;
}

#if defined(__has_builtin)
#if __has_builtin(__builtin_amdgcn_fdot2)
#define HAVE_FDOT2 1
#endif
#endif

__device__ __forceinline__ float fdot2f(h2v a, h2v b, float c) {
#ifdef HAVE_FDOT2
  return __builtin_amdgcn_fdot2(a, b, c, false);
#else
  return c + (float)a.x * (float)b.x + (float)a.y * (float)b.y;
#endif
}

// ---------------------------------------------------------------------------
// MFMA node projection: s = scaled_silu(X @ W1 + b1) @ W2 + b2 -> fp16 [N][384]
// Block: 256 threads (4 waves), 64 nodes. mfma_f32_16x16x32_f16.
// LDS: Xs[64][136] fp16 (X tile, then H tile in-place), Wt[128][136] fp16
// (transposed weight chunk: W1^T, then W2^T in 3 col-chunks of 128).
// 136-half row stride: 272B = 16B-aligned rows, ds_read_b128 frags ~2-way.
// Frag layouts: A[l&15][(l>>4)*8+j], B[(l>>4)*8+j][l&15],
// C/D: col=lane&15, row=(lane>>4)*4+reg  [m89-verified].
// ---------------------------------------------------------------------------
__device__ __forceinline__ void stage_wt(const float* __restrict__ W,
                                         _Float16* __restrict__ Wt, int t,
                                         int f4stride, int f4base) {
  const float4* Wv = reinterpret_cast<const float4*>(W);
#pragma unroll
  for (int i = 0; i < 8; ++i) {
    int pid = t + i * 256;            // 0..2047: 64 k-pairs x 32 n-float4s
    int k = (pid >> 5) * 2;
    int nf = pid & 31;
    float4 a = Wv[(size_t)k * f4stride + f4base + nf];
    float4 b = Wv[(size_t)(k + 1) * f4stride + f4base + nf];
    const float av[4] = {a.x, a.y, a.z, a.w};
    const float bv[4] = {b.x, b.y, b.z, b.w};
    const int n0 = nf * 4;
#pragma unroll
    for (int j = 0; j < 4; ++j)
      *reinterpret_cast<uint_t*>(&Wt[(n0 + j) * 136 + k]) =
          pack2h(av[j], bv[j]);
  }
}

__global__ __launch_bounds__(256) void proj_kernel(
    const float* __restrict__ X, const float* __restrict__ W1,
    const float* __restrict__ b1, const float* __restrict__ W2,
    const float* __restrict__ b2, ushort_t* __restrict__ s_half, int N) {
  __shared__ alignas(16) _Float16 Xs[64 * 136];   // X tile then H tile
  __shared__ alignas(16) _Float16 Wt[128 * 136];  // transposed weight chunk

  const int t = threadIdx.x;
  const int w = t >> 6;        // wave 0..3
  const int l = t & 63;        // lane
  const int nb = blockIdx.x * 64;

  // ---- stage X tile: [64][128] fp32 -> Xs[64][136] fp16 ----
  {
    const float4* Xv = reinterpret_cast<const float4*>(X);
#pragma unroll
    for (int i = 0; i < 8; ++i) {
      int g = t + i * 256;            // 0..2047
      int row = g >> 5, k0 = (g & 31) * 4;
      int node = nb + row;
      float4 v = (node < N) ? Xv[(size_t)nb * 32 + g]
                            : make_float4(0.f, 0.f, 0.f, 0.f);
      uint_t* dst = reinterpret_cast<uint_t*>(&Xs[row * 136 + k0]);
      dst[0] = pack2h(v.x, v.y);
      dst[1] = pack2h(v.z, v.w);
    }
  }
  // ---- stage W1^T ----
  stage_wt(W1, Wt, t, 32, 0);
  __syncthreads();

  const int arow = w * 16 + (l & 15);
  const int koff = (l >> 4) * 8;
  const int bcol = l & 15;

  // ---- phase 1: H = X @ W1 (each wave: 16 rows x 128 cols) ----
  half8_t af[4];
#pragma unroll
  for (int s = 0; s < 4; ++s)
    af[s] = *reinterpret_cast<const half8_t*>(&Xs[arow * 136 + s * 32 + koff]);

  float4_t acc[8];
#pragma unroll
  for (int c = 0; c < 8; ++c) {
    float4_t a = {0.f, 0.f, 0.f, 0.f};
#pragma unroll
    for (int s = 0; s < 4; ++s) {
      half8_t bf = *reinterpret_cast<const half8_t*>(
          &Wt[(c * 16 + bcol) * 136 + s * 32 + koff]);
      a = __builtin_amdgcn_mfma_f32_16x16x32_f16(af[s], bf, a, 0, 0, 0);
    }
    acc[c] = a;
  }

  __syncthreads();  // all Xs/Wt reads done before overwrite

  // ---- bias + scaled-silu -> H (fp16) into Xs; stage W2 chunk 0 ----
#pragma unroll
  for (int c = 0; c < 8; ++c) {
    const int col = c * 16 + bcol;
    const float bv = b1[col];
#pragma unroll
    for (int r = 0; r < 4; ++r) {
      const int row = w * 16 + (l >> 4) * 4 + r;
      float hv = acc[c][r] + bv;
      hv = hv * SILU_SCALE_F / (1.0f + expf(-hv));
      Xs[row * 136 + col] = (_Float16)hv;
    }
  }
  stage_wt(W2, Wt, t, 96, 0);
  __syncthreads();

  // ---- phase 2: S = H @ W2 + b2, 3 col-chunks of 128 ----
  half8_t ha[4];
#pragma unroll
  for (int s = 0; s < 4; ++s)
    ha[s] = *reinterpret_cast<const half8_t*>(&Xs[arow * 136 + s * 32 + koff]);

  for (int cn = 0; cn < 3; ++cn) {
    if (cn > 0) {
      __syncthreads();                // prev chunk's Wt reads done
      stage_wt(W2, Wt, t, 96, cn * 32);
      __syncthreads();
    }
#pragma unroll
    for (int c = 0; c < 8; ++c) {
      float4_t a = {0.f, 0.f, 0.f, 0.f};
#pragma unroll
      for (int s = 0; s < 4; ++s) {
        half8_t bf = *reinterpret_cast<const half8_t*>(
            &Wt[(c * 16 + bcol) * 136 + s * 32 + koff]);
        a = __builtin_amdgcn_mfma_f32_16x16x32_f16(ha[s], bf, a, 0, 0, 0);
      }
      const int gcol = cn * 128 + c * 16 + bcol;
      const float bv = b2[gcol];
#pragma unroll
      for (int r = 0; r < 4; ++r) {
        const int node = nb + w * 16 + (l >> 4) * 4 + r;
        if (node < N)
          s_half[(size_t)node * 384 + gcol] =
              __half_as_ushort(__float2half_rn(a[r] + bv));
      }
    }
  }
}

// ---------------------------------------------------------------------------
// vf fp32 -> fp16, pure elementwise (natural layout), fully vectorized.
// ---------------------------------------------------------------------------
__global__ void vf_cast_kernel(const float* __restrict__ vf,
                               ushort_t* __restrict__ vf_half, int total8) {
  int i = blockIdx.x * 256 + threadIdx.x;
  if (i >= total8) return;
  const float4* v4 = reinterpret_cast<const float4*>(vf);
  float4 a = v4[2 * i], b = v4[2 * i + 1];
  uint4 r = make_uint4(pack2h(a.x, a.y), pack2h(a.z, a.w),
                       pack2h(b.x, b.y), pack2h(b.z, b.w));
  reinterpret_cast<uint4*>(vf_half)[i] = r;
}

// ---------------------------------------------------------------------------
// CSR build
// ---------------------------------------------------------------------------
__global__ void zero_kernel(int* __restrict__ p, int n) {
  int i = blockIdx.x * 256 + threadIdx.x;
  if (i < n) p[i] = 0;
}

__global__ void hist_kernel(const int* __restrict__ tgt, int* __restrict__ counts,
                            int E) {
  int e = blockIdx.x * 256 + threadIdx.x;
  if (e < E) atomicAdd(&counts[tgt[e]], 1);
}

__global__ void chunk_sum_kernel(const int* __restrict__ counts,
                                 int* __restrict__ chunk_sums, int N) {
  __shared__ int red[256];
  int b = blockIdx.x, t = threadIdx.x;
  int base = b * 1024 + t * 4;
  int s = 0;
#pragma unroll
  for (int j = 0; j < 4; ++j) s += (base + j < N) ? counts[base + j] : 0;
  red[t] = s;
  __syncthreads();
  for (int off = 128; off > 0; off >>= 1) {
    if (t < off) red[t] += red[t + off];
    __syncthreads();
  }
  if (t == 0) chunk_sums[b] = red[0];
}

__global__ void scan_chunks_kernel(int* __restrict__ chunk_sums,
                                   int* __restrict__ offsets, int nch, int N,
                                   int E) {
  int t = threadIdx.x;  // one wave; nch <= 64
  int v = (t < nch) ? chunk_sums[t] : 0;
  int orig = v;
#pragma unroll
  for (int off = 1; off < 64; off <<= 1) {
    int y = __shfl_up(v, off);
    if (t >= off) v += y;
  }
  if (t < nch) chunk_sums[t] = v - orig;
  if (t == 0) offsets[N] = E;
}

__global__ void scan_block_kernel(const int* __restrict__ counts,
                                  const int* __restrict__ chunk_off,
                                  int* __restrict__ offsets,
                                  int* __restrict__ cursor, int N) {
  __shared__ int part[256];
  int b = blockIdx.x, t = threadIdx.x;
  int base = b * 1024 + t * 4;
  int v[4];
#pragma unroll
  for (int j = 0; j < 4; ++j) v[j] = (base + j < N) ? counts[base + j] : 0;
  int local = v[0] + v[1] + v[2] + v[3];
  part[t] = local;
  __syncthreads();
  for (int off = 1; off < 256; off <<= 1) {
    int x = 0;
    if (t >= off) x = part[t - off];
    __syncthreads();
    if (t >= off) part[t] += x;
    __syncthreads();
  }
  int run = chunk_off[b] + (part[t] - local);
#pragma unroll
  for (int j = 0; j < 4; ++j) {
    if (base + j < N) {
      offsets[base + j] = run;
      cursor[base + j] = run;
      run += v[j];
    }
  }
}

// ---------------------------------------------------------------------------
// Fused edge geometry + CSR scatter. rbf packed fp16 (10 x half2, stride 12
// uints for 16B alignment), dir fp32.
// ---------------------------------------------------------------------------
__global__ void edge_geom_kernel(const float* __restrict__ pos,
                                 const int* __restrict__ src,
                                 const int* __restrict__ tgt,
                                 int* __restrict__ cursor,
                                 float4* __restrict__ dir4_s,
                                 uint_t* __restrict__ rbh_s,
                                 int* __restrict__ src_s, int E) {
  int e = blockIdx.x * 256 + threadIdx.x;
  if (e >= E) return;
  const int sn = src[e];
  const int tn = tgt[e];
  const float rx = pos[tn * 3 + 0] - pos[sn * 3 + 0];
  const float ry = pos[tn * 3 + 1] - pos[sn * 3 + 1];
  const float rz = pos[tn * 3 + 2] - pos[sn * 3 + 2];
  const float dist = sqrtf(rx * rx + ry * ry + rz * rz);
  const float inv = 1.0f / dist;

  const float ang = dist * (PI_F / CUT_OFF_F);
  float s1, c1;
  sincosf(ang, &s1, &c1);
  float sk = s1, ck = c1;
  float rb[NUM_RBF];
  rb[0] = s1 * inv;
#pragma unroll
  for (int r = 1; r < NUM_RBF; ++r) {
    float sn2 = sk * c1 + ck * s1;
    ck = ck * c1 - sk * s1;
    sk = sn2;
    rb[r] = sk * inv;
  }

  const int p = atomicAdd(&cursor[tn], 1);
  dir4_s[p] = make_float4(rx * inv, ry * inv, rz * inv, dist);
  src_s[p] = sn;
  uint_t us[10];
#pragma unroll
  for (int q = 0; q < 10; ++q) us[q] = pack2h(rb[2 * q], rb[2 * q + 1]);
  uint_t* o = rbh_s + (size_t)p * 12;
  *reinterpret_cast<uint4*>(o) = make_uint4(us[0], us[1], us[2], us[3]);
  *reinterpret_cast<uint4*>(o + 4) = make_uint4(us[4], us[5], us[6], us[7]);
  *reinterpret_cast<uint2*>(o + 8) = make_uint2(us[8], us[9]);
}

// ---------------------------------------------------------------------------
// Node gather (R6 config, measured 171 us). fp16 natural-order gathers of
// s/vf, packed-fp16 rbf with v_dot2 filter dot, shfl-broadcast src, x2 ILP.
// ---------------------------------------------------------------------------
#define NODES_PER_BLOCK 16

__device__ __forceinline__ float cutoff_f(float x) {
  return (x < CUT_OFF_F) ? 0.5f * (1.0f + __cosf(x * (PI_F / CUT_OFF_F))) : 0.f;
}

struct EdgeData {
  float4 dir;
  uint_t rbu[10];
  float sx, sy, sz, vx, vy, vz;
};

__device__ __forceinline__ void load_edge(int idx, int sn, int d,
                                          const ushort_t* __restrict__ s_half,
                                          const ushort_t* __restrict__ vf_half,
                                          const float4* __restrict__ dir4_s,
                                          const uint_t* __restrict__ rbh_s,
                                          EdgeData& ed) {
  ed.dir = dir4_s[idx];
  const uint_t* o = rbh_s + (size_t)idx * 12;
  uint4 u0 = *reinterpret_cast<const uint4*>(o);
  uint4 u1 = *reinterpret_cast<const uint4*>(o + 4);
  uint2 u2 = *reinterpret_cast<const uint2*>(o + 8);
  ed.rbu[0] = u0.x; ed.rbu[1] = u0.y; ed.rbu[2] = u0.z; ed.rbu[3] = u0.w;
  ed.rbu[4] = u1.x; ed.rbu[5] = u1.y; ed.rbu[6] = u1.z; ed.rbu[7] = u1.w;
  ed.rbu[8] = u2.x; ed.rbu[9] = u2.y;
  const ushort_t* sr = s_half + (size_t)sn * 384 + 3 * d;
  ed.sx = h2f(sr[0]); ed.sy = h2f(sr[1]); ed.sz = h2f(sr[2]);
  const ushort_t* vr = vf_half + (size_t)sn * 384 + 3 * d;
  ed.vx = h2f(vr[0]); ed.vy = h2f(vr[1]); ed.vz = h2f(vr[2]);
}

__global__ __launch_bounds__(128) void node_kernel(
    const ushort_t* __restrict__ s_half, const ushort_t* __restrict__ vf_half,
    const float4* __restrict__ dir4_s, const uint_t* __restrict__ rbh_s,
    const int* __restrict__ src_s, const int* __restrict__ offsets,
    const float* __restrict__ Wr, const float* __restrict__ br,
    float* __restrict__ out, int N, int E) {
  const int d = threadIdx.x;
  const int lane = d & 63;

  h2v wr0h[10], wr1h[10], wr2h[10];
#pragma unroll
  for (int q = 0; q < 10; ++q) {
    h2v w;
    w.x = (_Float16)Wr[(2 * q) * 384 + 3 * d + 0];
    w.y = (_Float16)Wr[(2 * q + 1) * 384 + 3 * d + 0];
    wr0h[q] = w;
    w.x = (_Float16)Wr[(2 * q) * 384 + 3 * d + 1];
    w.y = (_Float16)Wr[(2 * q + 1) * 384 + 3 * d + 1];
    wr1h[q] = w;
    w.x = (_Float16)Wr[(2 * q) * 384 + 3 * d + 2];
    w.y = (_Float16)Wr[(2 * q + 1) * 384 + 3 * d + 2];
    wr2h[q] = w;
  }
  const float br0 = br[3 * d + 0];
  const float br1 = br[3 * d + 1];
  const float br2 = br[3 * d + 2];

  for (int nn = 0; nn < NODES_PER_BLOCK; ++nn) {
    const int n = blockIdx.x * NODES_PER_BLOCK + nn;
    if (n >= N) break;

    const int start = offsets[n];
    const int end = offsets[n + 1];

    float accs = 0.f, av0 = 0.f, av1 = 0.f, av2 = 0.f;

    for (int base = start; base < end; base += 64) {
      const int m = min(64, end - base);
      int ld = base + lane;
      if (ld >= E) ld = E - 1;
      const int sn_l = src_s[ld];

      int i = 0;
      for (; i + 2 <= m; i += 2) {
        const int sn0 = __shfl(sn_l, i);
        const int sn1 = __shfl(sn_l, i + 1);
        EdgeData e0, e1;
        load_edge(base + i, sn0, d, s_half, vf_half, dir4_s, rbh_s, e0);
        load_edge(base + i + 1, sn1, d, s_half, vf_half, dir4_s, rbh_s, e1);

#pragma unroll
        for (int u = 0; u < 2; ++u) {
          const EdgeData& ed = (u == 0) ? e0 : e1;
          float f0 = br0, f1 = br1, f2 = br2;
#pragma unroll
          for (int q = 0; q < 10; ++q) {
            h2v r = u2h2(ed.rbu[q]);
            f0 = fdot2f(r, wr0h[q], f0);
            f1 = fdot2f(r, wr1h[q], f1);
            f2 = fdot2f(r, wr2h[q], f2);
          }
          f0 = cutoff_f(f0);
          f1 = cutoff_f(f1);
          f2 = cutoff_f(f2);
          const float m0 = ed.sx * f0;
          const float m1 = ed.sy * f1;
          const float m2 = ed.sz * f2;
          accs += m0;
          av0 += m2 * ed.dir.x + m1 * ed.vx;
          av1 += m2 * ed.dir.y + m1 * ed.vy;
          av2 += m2 * ed.dir.z + m1 * ed.vz;
        }
      }
      if (i < m) {
        const int sn0 = __shfl(sn_l, i);
        EdgeData e0;
        load_edge(base + i, sn0, d, s_half, vf_half, dir4_s, rbh_s, e0);
        float f0 = br0, f1 = br1, f2 = br2;
#pragma unroll
        for (int q = 0; q < 10; ++q) {
          h2v r = u2h2(e0.rbu[q]);
          f0 = fdot2f(r, wr0h[q], f0);
          f1 = fdot2f(r, wr1h[q], f1);
          f2 = fdot2f(r, wr2h[q], f2);
        }
        f0 = cutoff_f(f0);
        f1 = cutoff_f(f1);
        f2 = cutoff_f(f2);
        const float m0 = e0.sx * f0;
        const float m1 = e0.sy * f1;
        const float m2 = e0.sz * f2;
        accs += m0;
        av0 += m2 * e0.dir.x + m1 * e0.vx;
        av1 += m2 * e0.dir.y + m1 * e0.vy;
        av2 += m2 * e0.dir.z + m1 * e0.vz;
      }
    }

    out[(size_t)n * 384 + 3 * d + 0] = av0;
    out[(size_t)n * 384 + 3 * d + 1] = av1;
    out[(size_t)n * 384 + 3 * d + 2] = av2;
    out[(size_t)N * 384 + (size_t)n * 128 + d] = accs;
  }
}

// ---------------------------------------------------------------------------
extern "C" void kernel_launch(void* const* d_in, const int* in_sizes, int n_in,
                              void* d_out, int out_size, void* d_ws,
                              size_t ws_size, hipStream_t stream) {
  const float* vf  = (const float*)d_in[0];   // [N,128,3]
  const float* X   = (const float*)d_in[1];   // [N,128]
  const float* pos = (const float*)d_in[2];   // [N,3]
  const int* ei    = (const int*)d_in[3];     // [2,E]
  const float* W1  = (const float*)d_in[4];
  const float* b1  = (const float*)d_in[5];
  const float* W2  = (const float*)d_in[6];
  const float* b2  = (const float*)d_in[7];
  const float* Wr  = (const float*)d_in[8];
  const float* br  = (const float*)d_in[9];

  const int N = in_sizes[1] / D_DIM;
  const int E = in_sizes[3] / 2;
  const int* srcI = ei;
  const int* tgtI = ei + E;
  float* out = (float*)d_out;

  // workspace layout (16B-aligned chunks first)
  char* w = (char*)d_ws;
  float4* dir4_s    = (float4*)w;   w += (size_t)E * sizeof(float4);
  uint_t* rbh_s     = (uint_t*)w;   w += (size_t)E * 12 * sizeof(uint_t);
  ushort_t* s_half  = (ushort_t*)w; w += (size_t)N * 384 * sizeof(ushort_t);
  ushort_t* vf_half = (ushort_t*)w; w += (size_t)N * 384 * sizeof(ushort_t);
  int* src_s        = (int*)w;      w += (size_t)E * sizeof(int);
  int* counts       = (int*)w;      w += (size_t)N * sizeof(int);
  int* offsets      = (int*)w;      w += (size_t)(N + 1) * sizeof(int);
  int* cursor       = (int*)w;      w += (size_t)N * sizeof(int);
  int* chunks       = (int*)w;      w += 64 * sizeof(int);

  const int nch = (N + 1023) / 1024;  // 49 for N=50000

  zero_kernel<<<(N + 255) / 256, 256, 0, stream>>>(counts, N);
  proj_kernel<<<(N + 63) / 64, 256, 0, stream>>>(X, W1, b1, W2, b2, s_half, N);
  vf_cast_kernel<<<(N * 384 / 8 + 255) / 256, 256, 0, stream>>>(vf, vf_half,
                                                                N * 384 / 8);
  hist_kernel<<<(E + 255) / 256, 256, 0, stream>>>(tgtI, counts, E);
  chunk_sum_kernel<<<nch, 256, 0, stream>>>(counts, chunks, N);
  scan_chunks_kernel<<<1, 64, 0, stream>>>(chunks, offsets, nch, N, E);
  scan_block_kernel<<<nch, 256, 0, stream>>>(counts, chunks, offsets, cursor, N);
  edge_geom_kernel<<<(E + 255) / 256, 256, 0, stream>>>(pos, srcI, tgtI, cursor,
                                                        dir4_s, rbh_s, src_s, E);
  node_kernel<<<(N + NODES_PER_BLOCK - 1) / NODES_PER_BLOCK, 128, 0, stream>>>(
      s_half, vf_half, dir4_s, rbh_s, src_s, offsets, Wr, br, out, N, E);
}

// Round 10
// 307.080 us; speedup vs baseline: 1.1517x; 1.0149x over previous
//
#include <hip/hip_runtime.h>
#include <hip/hip_fp16.h>
#include <math.h>
#include <stddef.h>

#define D_DIM 128
#define NUM_RBF 20
typedef unsigned short ushort_t;
typedef unsigned int uint_t;
typedef _Float16 h2v __attribute__((ext_vector_type(2)));
typedef _Float16 half8_t __attribute__((ext_vector_type(8)));
typedef float float4_t __attribute__((ext_vector_type(4)));
constexpr float PI_F = 3.14159265358979323846f;
constexpr float CUT_OFF_F = 5.0f;
constexpr float SILU_SCALE_F = 1.0f / 0.6f;

__device__ __forceinline__ uint_t pack2h(float a, float b) {
  __half2 h2 = __floats2half2_rn(a, b);
  return *reinterpret_cast<uint_t*>(&h2);
}
__device__ __forceinline__ float h2f(ushort_t u) {
  __half h = __ushort_as_half(u);
  return __half2float(h);
}
__device__ __forceinline__ float h2f_lo(uint_t u) { return h2f((ushort_t)(u & 0xffffu)); }
__device__ __forceinline__ float h2f_hi(uint_t u) { return h2f((ushort_t)(u >> 16)); }
__device__ __forceinline__ h2v u2h2(uint_t u) {
  h2v r;
  __builtin_memcpy(&r, &u, 4);
  return r;
}

#if defined(__has_builtin)
#if __has_builtin(__builtin_amdgcn_fdot2)
#define HAVE_FDOT2 1
#endif
#endif

__device__ __forceinline__ float fdot2f(h2v a, h2v b, float c) {
#ifdef HAVE_FDOT2
  return __builtin_amdgcn_fdot2(a, b, c, false);
#else
  return c + (float)a.x * (float)b.x + (float)a.y * (float)b.y;
#endif
}

// ---------------------------------------------------------------------------
// MFMA node projection + merged-buffer build.
// s = scaled_silu(X @ W1 + b1) @ W2 + b2 via mfma_f32_16x16x32_f16
// (R9-verified fragment layouts). Phase-2 results are kept packed in
// registers (static indexing, cn-loop unrolled), then one LDS bounce to
// sh[64][392] fp16 natural order, then a cooperative pass streams vf fp32
// and writes merged[N][128][3 uints] = {s3d|s3d+1, s3d+2|v0, v1|v2}.
// Replaces the standalone vf_cast kernel.
// LDS: one 26112-half pool (Xs 8704 + Wt 17408; reused as sh 25088).
// ---------------------------------------------------------------------------
__device__ __forceinline__ void stage_wt(const float* __restrict__ W,
                                         _Float16* __restrict__ Wt, int t,
                                         int f4stride, int f4base) {
  const float4* Wv = reinterpret_cast<const float4*>(W);
#pragma unroll
  for (int i = 0; i < 8; ++i) {
    int pid = t + i * 256;            // 0..2047: 64 k-pairs x 32 n-float4s
    int k = (pid >> 5) * 2;
    int nf = pid & 31;
    float4 a = Wv[(size_t)k * f4stride + f4base + nf];
    float4 b = Wv[(size_t)(k + 1) * f4stride + f4base + nf];
    const float av[4] = {a.x, a.y, a.z, a.w};
    const float bv[4] = {b.x, b.y, b.z, b.w};
    const int n0 = nf * 4;
#pragma unroll
    for (int j = 0; j < 4; ++j)
      *reinterpret_cast<uint_t*>(&Wt[(n0 + j) * 136 + k]) =
          pack2h(av[j], bv[j]);
  }
}

__global__ __launch_bounds__(256) void proj_kernel(
    const float* __restrict__ X, const float* __restrict__ W1,
    const float* __restrict__ b1, const float* __restrict__ W2,
    const float* __restrict__ b2, const float* __restrict__ vf,
    uint_t* __restrict__ merged, int N) {
  __shared__ alignas(16) _Float16 smem[26112];  // Xs[64*136] + Wt[128*136]
  _Float16* Xs = smem;
  _Float16* Wt = smem + 8704;

  const int t = threadIdx.x;
  const int w = t >> 6;        // wave 0..3
  const int l = t & 63;        // lane
  const int nb = blockIdx.x * 64;

  // ---- stage X tile: [64][128] fp32 -> Xs[64][136] fp16 ----
  {
    const float4* Xv = reinterpret_cast<const float4*>(X);
#pragma unroll
    for (int i = 0; i < 8; ++i) {
      int g = t + i * 256;            // 0..2047
      int row = g >> 5, k0 = (g & 31) * 4;
      int node = nb + row;
      float4 v = (node < N) ? Xv[(size_t)nb * 32 + g]
                            : make_float4(0.f, 0.f, 0.f, 0.f);
      uint_t* dst = reinterpret_cast<uint_t*>(&Xs[row * 136 + k0]);
      dst[0] = pack2h(v.x, v.y);
      dst[1] = pack2h(v.z, v.w);
    }
  }
  stage_wt(W1, Wt, t, 32, 0);
  __syncthreads();

  const int arow = w * 16 + (l & 15);
  const int koff = (l >> 4) * 8;
  const int bcol = l & 15;

  // ---- phase 1: H = X @ W1 ----
  half8_t af[4];
#pragma unroll
  for (int s = 0; s < 4; ++s)
    af[s] = *reinterpret_cast<const half8_t*>(&Xs[arow * 136 + s * 32 + koff]);

  float4_t acc[8];
#pragma unroll
  for (int c = 0; c < 8; ++c) {
    float4_t a = {0.f, 0.f, 0.f, 0.f};
#pragma unroll
    for (int s = 0; s < 4; ++s) {
      half8_t bf = *reinterpret_cast<const half8_t*>(
          &Wt[(c * 16 + bcol) * 136 + s * 32 + koff]);
      a = __builtin_amdgcn_mfma_f32_16x16x32_f16(af[s], bf, a, 0, 0, 0);
    }
    acc[c] = a;
  }

  __syncthreads();  // all Xs/Wt reads done before overwrite

  // ---- bias + scaled-silu -> H (fp16) into Xs; stage W2 chunk 0 ----
#pragma unroll
  for (int c = 0; c < 8; ++c) {
    const int col = c * 16 + bcol;
    const float bv = b1[col];
#pragma unroll
    for (int r = 0; r < 4; ++r) {
      const int row = w * 16 + (l >> 4) * 4 + r;
      float hv = acc[c][r] + bv;
      hv = hv * SILU_SCALE_F / (1.0f + expf(-hv));
      Xs[row * 136 + col] = (_Float16)hv;
    }
  }
  stage_wt(W2, Wt, t, 96, 0);
  __syncthreads();

  // ---- phase 2: S = H @ W2 + b2, 3 col-chunks of 128; results in regs ----
  half8_t ha[4];
#pragma unroll
  for (int s = 0; s < 4; ++s)
    ha[s] = *reinterpret_cast<const half8_t*>(&Xs[arow * 136 + s * 32 + koff]);

  uint_t pk[3][8][2];   // packed fp16 results; fully static indexing
#pragma unroll
  for (int cn = 0; cn < 3; ++cn) {
    if (cn > 0) {
      __syncthreads();                // prev chunk's Wt reads done
      stage_wt(W2, Wt, t, 96, cn * 32);
      __syncthreads();
    }
#pragma unroll
    for (int c = 0; c < 8; ++c) {
      float4_t a = {0.f, 0.f, 0.f, 0.f};
#pragma unroll
      for (int s = 0; s < 4; ++s) {
        half8_t bf = *reinterpret_cast<const half8_t*>(
            &Wt[(c * 16 + bcol) * 136 + s * 32 + koff]);
        a = __builtin_amdgcn_mfma_f32_16x16x32_f16(ha[s], bf, a, 0, 0, 0);
      }
      const float bv = b2[cn * 128 + c * 16 + bcol];
      pk[cn][c][0] = pack2h(a[0] + bv, a[1] + bv);
      pk[cn][c][1] = pack2h(a[2] + bv, a[3] + bv);
    }
  }

  // ---- bounce S to LDS natural [64][392] ----
  __syncthreads();                    // all Wt reads done; smem reusable
  ushort_t* sh = reinterpret_cast<ushort_t*>(smem);
  {
    const int rbase = w * 16 + (l >> 4) * 4;
#pragma unroll
    for (int cn = 0; cn < 3; ++cn)
#pragma unroll
      for (int c = 0; c < 8; ++c) {
        const int gcol = cn * 128 + c * 16 + bcol;
        sh[(rbase + 0) * 392 + gcol] = (ushort_t)(pk[cn][c][0] & 0xffffu);
        sh[(rbase + 1) * 392 + gcol] = (ushort_t)(pk[cn][c][0] >> 16);
        sh[(rbase + 2) * 392 + gcol] = (ushort_t)(pk[cn][c][1] & 0xffffu);
        sh[(rbase + 3) * 392 + gcol] = (ushort_t)(pk[cn][c][1] >> 16);
      }
  }
  __syncthreads();

  // ---- merged build: stream vf, write {s|s, s|v, v|v} per (node,chan) ----
#pragma unroll 4
  for (int k = 0; k < 32; ++k) {
    const int P = k * 256 + t;        // 0..8191
    const int ln = P >> 7;            // local node 0..63
    const int chan = P & 127;
    const int node = nb + ln;
    if (node < N) {
      const ushort_t* sp = &sh[ln * 392 + 3 * chan];
      const float* vp = vf + ((size_t)node * 128 + chan) * 3;
      uint_t* mp = merged + ((size_t)node * 128 + chan) * 3;
      mp[0] = (uint_t)sp[0] | ((uint_t)sp[1] << 16);
      mp[1] = (uint_t)sp[2] |
              ((uint_t)__half_as_ushort(__float2half_rn(vp[0])) << 16);
      mp[2] = pack2h(vp[1], vp[2]);
    }
  }
}

// ---------------------------------------------------------------------------
// CSR build
// ---------------------------------------------------------------------------
__global__ void zero_kernel(int* __restrict__ p, int n) {
  int i = blockIdx.x * 256 + threadIdx.x;
  if (i < n) p[i] = 0;
}

__global__ void hist_kernel(const int* __restrict__ tgt, int* __restrict__ counts,
                            int E) {
  int e = blockIdx.x * 256 + threadIdx.x;
  if (e < E) atomicAdd(&counts[tgt[e]], 1);
}

__global__ void chunk_sum_kernel(const int* __restrict__ counts,
                                 int* __restrict__ chunk_sums, int N) {
  __shared__ int red[256];
  int b = blockIdx.x, t = threadIdx.x;
  int base = b * 1024 + t * 4;
  int s = 0;
#pragma unroll
  for (int j = 0; j < 4; ++j) s += (base + j < N) ? counts[base + j] : 0;
  red[t] = s;
  __syncthreads();
  for (int off = 128; off > 0; off >>= 1) {
    if (t < off) red[t] += red[t + off];
    __syncthreads();
  }
  if (t == 0) chunk_sums[b] = red[0];
}

__global__ void scan_chunks_kernel(int* __restrict__ chunk_sums,
                                   int* __restrict__ offsets, int nch, int N,
                                   int E) {
  int t = threadIdx.x;  // one wave; nch <= 64
  int v = (t < nch) ? chunk_sums[t] : 0;
  int orig = v;
#pragma unroll
  for (int off = 1; off < 64; off <<= 1) {
    int y = __shfl_up(v, off);
    if (t >= off) v += y;
  }
  if (t < nch) chunk_sums[t] = v - orig;
  if (t == 0) offsets[N] = E;
}

__global__ void scan_block_kernel(const int* __restrict__ counts,
                                  const int* __restrict__ chunk_off,
                                  int* __restrict__ offsets,
                                  int* __restrict__ cursor, int N) {
  __shared__ int part[256];
  int b = blockIdx.x, t = threadIdx.x;
  int base = b * 1024 + t * 4;
  int v[4];
#pragma unroll
  for (int j = 0; j < 4; ++j) v[j] = (base + j < N) ? counts[base + j] : 0;
  int local = v[0] + v[1] + v[2] + v[3];
  part[t] = local;
  __syncthreads();
  for (int off = 1; off < 256; off <<= 1) {
    int x = 0;
    if (t >= off) x = part[t - off];
    __syncthreads();
    if (t >= off) part[t] += x;
    __syncthreads();
  }
  int run = chunk_off[b] + (part[t] - local);
#pragma unroll
  for (int j = 0; j < 4; ++j) {
    if (base + j < N) {
      offsets[base + j] = run;
      cursor[base + j] = run;
      run += v[j];
    }
  }
}

// ---------------------------------------------------------------------------
// Fused edge geometry + CSR scatter. rbf packed fp16 (10 x half2, stride 12
// uints for 16B alignment), dir fp32.
// ---------------------------------------------------------------------------
__global__ void edge_geom_kernel(const float* __restrict__ pos,
                                 const int* __restrict__ src,
                                 const int* __restrict__ tgt,
                                 int* __restrict__ cursor,
                                 float4* __restrict__ dir4_s,
                                 uint_t* __restrict__ rbh_s,
                                 int* __restrict__ src_s, int E) {
  int e = blockIdx.x * 256 + threadIdx.x;
  if (e >= E) return;
  const int sn = src[e];
  const int tn = tgt[e];
  const float rx = pos[tn * 3 + 0] - pos[sn * 3 + 0];
  const float ry = pos[tn * 3 + 1] - pos[sn * 3 + 1];
  const float rz = pos[tn * 3 + 2] - pos[sn * 3 + 2];
  const float dist = sqrtf(rx * rx + ry * ry + rz * rz);
  const float inv = 1.0f / dist;

  const float ang = dist * (PI_F / CUT_OFF_F);
  float s1, c1;
  sincosf(ang, &s1, &c1);
  float sk = s1, ck = c1;
  float rb[NUM_RBF];
  rb[0] = s1 * inv;
#pragma unroll
  for (int r = 1; r < NUM_RBF; ++r) {
    float sn2 = sk * c1 + ck * s1;
    ck = ck * c1 - sk * s1;
    sk = sn2;
    rb[r] = sk * inv;
  }

  const int p = atomicAdd(&cursor[tn], 1);
  dir4_s[p] = make_float4(rx * inv, ry * inv, rz * inv, dist);
  src_s[p] = sn;
  uint_t us[10];
#pragma unroll
  for (int q = 0; q < 10; ++q) us[q] = pack2h(rb[2 * q], rb[2 * q + 1]);
  uint_t* o = rbh_s + (size_t)p * 12;
  *reinterpret_cast<uint4*>(o) = make_uint4(us[0], us[1], us[2], us[3]);
  *reinterpret_cast<uint4*>(o + 4) = make_uint4(us[4], us[5], us[6], us[7]);
  *reinterpret_cast<uint2*>(o + 8) = make_uint2(us[8], us[9]);
}

// ---------------------------------------------------------------------------
// Node gather (R7-proven merged version). Single merged fp16 gather (3 uints,
// one base) per edge-lane, packed-fp16 rbf with v_dot2 filter dot,
// shfl-broadcast src, x2 ILP.
// ---------------------------------------------------------------------------
#define NODES_PER_BLOCK 8

__device__ __forceinline__ float cutoff_f(float x) {
  return (x < CUT_OFF_F) ? 0.5f * (1.0f + __cosf(x * (PI_F / CUT_OFF_F))) : 0.f;
}

struct EdgeData {
  float4 dir;
  uint_t rbu[10];
  uint_t su[3];
};

__device__ __forceinline__ void load_edge(int idx, int sn, int d,
                                          const uint_t* __restrict__ merged,
                                          const float4* __restrict__ dir4_s,
                                          const uint_t* __restrict__ rbh_s,
                                          EdgeData& ed) {
  ed.dir = dir4_s[idx];
  const uint_t* o = rbh_s + (size_t)idx * 12;
  uint4 u0 = *reinterpret_cast<const uint4*>(o);
  uint4 u1 = *reinterpret_cast<const uint4*>(o + 4);
  uint2 u2 = *reinterpret_cast<const uint2*>(o + 8);
  ed.rbu[0] = u0.x; ed.rbu[1] = u0.y; ed.rbu[2] = u0.z; ed.rbu[3] = u0.w;
  ed.rbu[4] = u1.x; ed.rbu[5] = u1.y; ed.rbu[6] = u1.z; ed.rbu[7] = u1.w;
  ed.rbu[8] = u2.x; ed.rbu[9] = u2.y;
  const uint_t* mp = merged + ((size_t)sn * 128 + d) * 3;
  ed.su[0] = mp[0]; ed.su[1] = mp[1]; ed.su[2] = mp[2];
}

__global__ __launch_bounds__(128) void node_kernel(
    const uint_t* __restrict__ merged, const float4* __restrict__ dir4_s,
    const uint_t* __restrict__ rbh_s, const int* __restrict__ src_s,
    const int* __restrict__ offsets, const float* __restrict__ Wr,
    const float* __restrict__ br, float* __restrict__ out, int N, int E) {
  const int d = threadIdx.x;
  const int lane = d & 63;

  h2v wr0h[10], wr1h[10], wr2h[10];
#pragma unroll
  for (int q = 0; q < 10; ++q) {
    h2v w;
    w.x = (_Float16)Wr[(2 * q) * 384 + 3 * d + 0];
    w.y = (_Float16)Wr[(2 * q + 1) * 384 + 3 * d + 0];
    wr0h[q] = w;
    w.x = (_Float16)Wr[(2 * q) * 384 + 3 * d + 1];
    w.y = (_Float16)Wr[(2 * q + 1) * 384 + 3 * d + 1];
    wr1h[q] = w;
    w.x = (_Float16)Wr[(2 * q) * 384 + 3 * d + 2];
    w.y = (_Float16)Wr[(2 * q + 1) * 384 + 3 * d + 2];
    wr2h[q] = w;
  }
  const float br0 = br[3 * d + 0];
  const float br1 = br[3 * d + 1];
  const float br2 = br[3 * d + 2];

  for (int nn = 0; nn < NODES_PER_BLOCK; ++nn) {
    const int n = blockIdx.x * NODES_PER_BLOCK + nn;
    if (n >= N) break;

    const int start = offsets[n];
    const int end = offsets[n + 1];

    float accs = 0.f, av0 = 0.f, av1 = 0.f, av2 = 0.f;

    for (int base = start; base < end; base += 64) {
      const int m = min(64, end - base);
      int ld = base + lane;
      if (ld >= E) ld = E - 1;
      const int sn_l = src_s[ld];

      int i = 0;
      for (; i + 2 <= m; i += 2) {
        const int sn0 = __shfl(sn_l, i);
        const int sn1 = __shfl(sn_l, i + 1);
        EdgeData e0, e1;
        load_edge(base + i, sn0, d, merged, dir4_s, rbh_s, e0);
        load_edge(base + i + 1, sn1, d, merged, dir4_s, rbh_s, e1);

#pragma unroll
        for (int u = 0; u < 2; ++u) {
          const EdgeData& ed = (u == 0) ? e0 : e1;
          float f0 = br0, f1 = br1, f2 = br2;
#pragma unroll
          for (int q = 0; q < 10; ++q) {
            h2v r = u2h2(ed.rbu[q]);
            f0 = fdot2f(r, wr0h[q], f0);
            f1 = fdot2f(r, wr1h[q], f1);
            f2 = fdot2f(r, wr2h[q], f2);
          }
          f0 = cutoff_f(f0);
          f1 = cutoff_f(f1);
          f2 = cutoff_f(f2);
          const float m0 = h2f_lo(ed.su[0]) * f0;
          const float m1 = h2f_hi(ed.su[0]) * f1;
          const float m2 = h2f_lo(ed.su[1]) * f2;
          accs += m0;
          av0 += m2 * ed.dir.x + m1 * h2f_hi(ed.su[1]);
          av1 += m2 * ed.dir.y + m1 * h2f_lo(ed.su[2]);
          av2 += m2 * ed.dir.z + m1 * h2f_hi(ed.su[2]);
        }
      }
      if (i < m) {
        const int sn0 = __shfl(sn_l, i);
        EdgeData e0;
        load_edge(base + i, sn0, d, merged, dir4_s, rbh_s, e0);
        float f0 = br0, f1 = br1, f2 = br2;
#pragma unroll
        for (int q = 0; q < 10; ++q) {
          h2v r = u2h2(e0.rbu[q]);
          f0 = fdot2f(r, wr0h[q], f0);
          f1 = fdot2f(r, wr1h[q], f1);
          f2 = fdot2f(r, wr2h[q], f2);
        }
        f0 = cutoff_f(f0);
        f1 = cutoff_f(f1);
        f2 = cutoff_f(f2);
        const float m0 = h2f_lo(e0.su[0]) * f0;
        const float m1 = h2f_hi(e0.su[0]) * f1;
        const float m2 = h2f_lo(e0.su[1]) * f2;
        accs += m0;
        av0 += m2 * e0.dir.x + m1 * h2f_hi(e0.su[1]);
        av1 += m2 * e0.dir.y + m1 * h2f_lo(e0.su[2]);
        av2 += m2 * e0.dir.z + m1 * h2f_hi(e0.su[2]);
      }
    }

    out[(size_t)n * 384 + 3 * d + 0] = av0;
    out[(size_t)n * 384 + 3 * d + 1] = av1;
    out[(size_t)n * 384 + 3 * d + 2] = av2;
    out[(size_t)N * 384 + (size_t)n * 128 + d] = accs;
  }
}

// ---------------------------------------------------------------------------
extern "C" void kernel_launch(void* const* d_in, const int* in_sizes, int n_in,
                              void* d_out, int out_size, void* d_ws,
                              size_t ws_size, hipStream_t stream) {
  const float* vf  = (const float*)d_in[0];   // [N,128,3]
  const float* X   = (const float*)d_in[1];   // [N,128]
  const float* pos = (const float*)d_in[2];   // [N,3]
  const int* ei    = (const int*)d_in[3];     // [2,E]
  const float* W1  = (const float*)d_in[4];
  const float* b1  = (const float*)d_in[5];
  const float* W2  = (const float*)d_in[6];
  const float* b2  = (const float*)d_in[7];
  const float* Wr  = (const float*)d_in[8];
  const float* br  = (const float*)d_in[9];

  const int N = in_sizes[1] / D_DIM;
  const int E = in_sizes[3] / 2;
  const int* srcI = ei;
  const int* tgtI = ei + E;
  float* out = (float*)d_out;

  // workspace layout (16B-aligned chunks first)
  char* w = (char*)d_ws;
  float4* dir4_s = (float4*)w;  w += (size_t)E * sizeof(float4);
  uint_t* rbh_s  = (uint_t*)w;  w += (size_t)E * 12 * sizeof(uint_t);
  uint_t* merged = (uint_t*)w;  w += (size_t)N * 128 * 3 * sizeof(uint_t);
  int* src_s     = (int*)w;     w += (size_t)E * sizeof(int);
  int* counts    = (int*)w;     w += (size_t)N * sizeof(int);
  int* offsets   = (int*)w;     w += (size_t)(N + 1) * sizeof(int);
  int* cursor    = (int*)w;     w += (size_t)N * sizeof(int);
  int* chunks    = (int*)w;     w += 64 * sizeof(int);

  const int nch = (N + 1023) / 1024;  // 49 for N=50000

  zero_kernel<<<(N + 255) / 256, 256, 0, stream>>>(counts, N);
  proj_kernel<<<(N + 63) / 64, 256, 0, stream>>>(X, W1, b1, W2, b2, vf, merged,
                                                 N);
  hist_kernel<<<(E + 255) / 256, 256, 0, stream>>>(tgtI, counts, E);
  chunk_sum_kernel<<<nch, 256, 0, stream>>>(counts, chunks, N);
  scan_chunks_kernel<<<1, 64, 0, stream>>>(chunks, offsets, nch, N, E);
  scan_block_kernel<<<nch, 256, 0, stream>>>(counts, chunks, offsets, cursor, N);
  edge_geom_kernel<<<(E + 255) / 256, 256, 0, stream>>>(pos, srcI, tgtI, cursor,
                                                        dir4_s, rbh_s, src_s, E);
  node_kernel<<<(N + NODES_PER_BLOCK - 1) / NODES_PER_BLOCK, 128, 0, stream>>>(
      merged, dir4_s, rbh_s, src_s, offsets, Wr, br, out, N, E);
}

// Round 11
// 297.167 us; speedup vs baseline: 1.1901x; 1.0334x over previous
//
#include <hip/hip_runtime.h>
#include <hip/hip_fp16.h>
#include <math.h>
#include <stddef.h>

#define D_DIM 128
#define NUM_RBF 20
typedef unsigned short ushort_t;
typedef unsigned int uint_t;
typedef _Float16 h2v __attribute__((ext_vector_type(2)));
typedef _Float16 half8_t __attribute__((ext_vector_type(8)));
typedef float float4_t __attribute__((ext_vector_type(4)));
constexpr float PI_F = 3.14159265358979323846f;
constexpr float CUT_OFF_F = 5.0f;
constexpr float SILU_SCALE_F = 1.0f / 0.6f;

__device__ __forceinline__ uint_t pack2h(float a, float b) {
  __half2 h2 = __floats2half2_rn(a, b);
  return *reinterpret_cast<uint_t*>(&h2);
}
__device__ __forceinline__ float h2f(ushort_t u) {
  __half h = __ushort_as_half(u);
  return __half2float(h);
}
__device__ __forceinline__ float h2f_lo(uint_t u) { return h2f((ushort_t)(u & 0xffffu)); }
__device__ __forceinline__ float h2f_hi(uint_t u) { return h2f((ushort_t)(u >> 16)); }
__device__ __forceinline__ h2v u2h2(uint_t u) {
  h2v r;
  __builtin_memcpy(&r, &u, 4);
  return r;
}

#if defined(__has_builtin)
#if __has_builtin(__builtin_amdgcn_fdot2)
#define HAVE_FDOT2 1
#endif
#endif

__device__ __forceinline__ float fdot2f(h2v a, h2v b, float c) {
#ifdef HAVE_FDOT2
  return __builtin_amdgcn_fdot2(a, b, c, false);
#else
  return c + (float)a.x * (float)b.x + (float)a.y * (float)b.y;
#endif
}

// ---------------------------------------------------------------------------
// MFMA node projection + merged-buffer build (R10-verified) + counts zeroing.
// ---------------------------------------------------------------------------
__device__ __forceinline__ void stage_wt(const float* __restrict__ W,
                                         _Float16* __restrict__ Wt, int t,
                                         int f4stride, int f4base) {
  const float4* Wv = reinterpret_cast<const float4*>(W);
#pragma unroll
  for (int i = 0; i < 8; ++i) {
    int pid = t + i * 256;            // 0..2047: 64 k-pairs x 32 n-float4s
    int k = (pid >> 5) * 2;
    int nf = pid & 31;
    float4 a = Wv[(size_t)k * f4stride + f4base + nf];
    float4 b = Wv[(size_t)(k + 1) * f4stride + f4base + nf];
    const float av[4] = {a.x, a.y, a.z, a.w};
    const float bv[4] = {b.x, b.y, b.z, b.w};
    const int n0 = nf * 4;
#pragma unroll
    for (int j = 0; j < 4; ++j)
      *reinterpret_cast<uint_t*>(&Wt[(n0 + j) * 136 + k]) =
          pack2h(av[j], bv[j]);
  }
}

__global__ __launch_bounds__(256) void proj_kernel(
    const float* __restrict__ X, const float* __restrict__ W1,
    const float* __restrict__ b1, const float* __restrict__ W2,
    const float* __restrict__ b2, const float* __restrict__ vf,
    uint_t* __restrict__ merged, int* __restrict__ counts, int N) {
  __shared__ alignas(16) _Float16 smem[26112];  // Xs[64*136] + Wt[128*136]
  _Float16* Xs = smem;
  _Float16* Wt = smem + 8704;

  const int t = threadIdx.x;
  const int w = t >> 6;        // wave 0..3
  const int l = t & 63;        // lane
  const int nb = blockIdx.x * 64;

  // ---- fold-in: zero the CSR counts array (replaces zero_kernel) ----
  {
    int z = blockIdx.x * 256 + t;
    if (z < N) counts[z] = 0;
  }

  // ---- stage X tile: [64][128] fp32 -> Xs[64][136] fp16 ----
  {
    const float4* Xv = reinterpret_cast<const float4*>(X);
#pragma unroll
    for (int i = 0; i < 8; ++i) {
      int g = t + i * 256;            // 0..2047
      int row = g >> 5, k0 = (g & 31) * 4;
      int node = nb + row;
      float4 v = (node < N) ? Xv[(size_t)nb * 32 + g]
                            : make_float4(0.f, 0.f, 0.f, 0.f);
      uint_t* dst = reinterpret_cast<uint_t*>(&Xs[row * 136 + k0]);
      dst[0] = pack2h(v.x, v.y);
      dst[1] = pack2h(v.z, v.w);
    }
  }
  stage_wt(W1, Wt, t, 32, 0);
  __syncthreads();

  const int arow = w * 16 + (l & 15);
  const int koff = (l >> 4) * 8;
  const int bcol = l & 15;

  // ---- phase 1: H = X @ W1 ----
  half8_t af[4];
#pragma unroll
  for (int s = 0; s < 4; ++s)
    af[s] = *reinterpret_cast<const half8_t*>(&Xs[arow * 136 + s * 32 + koff]);

  float4_t acc[8];
#pragma unroll
  for (int c = 0; c < 8; ++c) {
    float4_t a = {0.f, 0.f, 0.f, 0.f};
#pragma unroll
    for (int s = 0; s < 4; ++s) {
      half8_t bf = *reinterpret_cast<const half8_t*>(
          &Wt[(c * 16 + bcol) * 136 + s * 32 + koff]);
      a = __builtin_amdgcn_mfma_f32_16x16x32_f16(af[s], bf, a, 0, 0, 0);
    }
    acc[c] = a;
  }

  __syncthreads();  // all Xs/Wt reads done before overwrite

  // ---- bias + scaled-silu -> H (fp16) into Xs; stage W2 chunk 0 ----
#pragma unroll
  for (int c = 0; c < 8; ++c) {
    const int col = c * 16 + bcol;
    const float bv = b1[col];
#pragma unroll
    for (int r = 0; r < 4; ++r) {
      const int row = w * 16 + (l >> 4) * 4 + r;
      float hv = acc[c][r] + bv;
      hv = hv * SILU_SCALE_F / (1.0f + expf(-hv));
      Xs[row * 136 + col] = (_Float16)hv;
    }
  }
  stage_wt(W2, Wt, t, 96, 0);
  __syncthreads();

  // ---- phase 2: S = H @ W2 + b2, 3 col-chunks of 128; results in regs ----
  half8_t ha[4];
#pragma unroll
  for (int s = 0; s < 4; ++s)
    ha[s] = *reinterpret_cast<const half8_t*>(&Xs[arow * 136 + s * 32 + koff]);

  uint_t pk[3][8][2];   // packed fp16 results; fully static indexing
#pragma unroll
  for (int cn = 0; cn < 3; ++cn) {
    if (cn > 0) {
      __syncthreads();                // prev chunk's Wt reads done
      stage_wt(W2, Wt, t, 96, cn * 32);
      __syncthreads();
    }
#pragma unroll
    for (int c = 0; c < 8; ++c) {
      float4_t a = {0.f, 0.f, 0.f, 0.f};
#pragma unroll
      for (int s = 0; s < 4; ++s) {
        half8_t bf = *reinterpret_cast<const half8_t*>(
            &Wt[(c * 16 + bcol) * 136 + s * 32 + koff]);
        a = __builtin_amdgcn_mfma_f32_16x16x32_f16(ha[s], bf, a, 0, 0, 0);
      }
      const float bv = b2[cn * 128 + c * 16 + bcol];
      pk[cn][c][0] = pack2h(a[0] + bv, a[1] + bv);
      pk[cn][c][1] = pack2h(a[2] + bv, a[3] + bv);
    }
  }

  // ---- bounce S to LDS natural [64][392] ----
  __syncthreads();                    // all Wt reads done; smem reusable
  ushort_t* sh = reinterpret_cast<ushort_t*>(smem);
  {
    const int rbase = w * 16 + (l >> 4) * 4;
#pragma unroll
    for (int cn = 0; cn < 3; ++cn)
#pragma unroll
      for (int c = 0; c < 8; ++c) {
        const int gcol = cn * 128 + c * 16 + bcol;
        sh[(rbase + 0) * 392 + gcol] = (ushort_t)(pk[cn][c][0] & 0xffffu);
        sh[(rbase + 1) * 392 + gcol] = (ushort_t)(pk[cn][c][0] >> 16);
        sh[(rbase + 2) * 392 + gcol] = (ushort_t)(pk[cn][c][1] & 0xffffu);
        sh[(rbase + 3) * 392 + gcol] = (ushort_t)(pk[cn][c][1] >> 16);
      }
  }
  __syncthreads();

  // ---- merged build: stream vf, write {s|s, s|v, v|v} per (node,chan) ----
#pragma unroll 4
  for (int k = 0; k < 32; ++k) {
    const int P = k * 256 + t;        // 0..8191
    const int ln = P >> 7;            // local node 0..63
    const int chan = P & 127;
    const int node = nb + ln;
    if (node < N) {
      const ushort_t* sp = &sh[ln * 392 + 3 * chan];
      const float* vp = vf + ((size_t)node * 128 + chan) * 3;
      uint_t* mp = merged + ((size_t)node * 128 + chan) * 3;
      mp[0] = (uint_t)sp[0] | ((uint_t)sp[1] << 16);
      mp[1] = (uint_t)sp[2] |
              ((uint_t)__half_as_ushort(__float2half_rn(vp[0])) << 16);
      mp[2] = pack2h(vp[1], vp[2]);
    }
  }
}

// ---------------------------------------------------------------------------
// CSR build (3 kernels: hist, chunk_sum, scan_block-with-inline-chunk-scan)
// ---------------------------------------------------------------------------
__global__ void hist_kernel(const int* __restrict__ tgt, int* __restrict__ counts,
                            int E) {
  int e = blockIdx.x * 256 + threadIdx.x;
  if (e < E) atomicAdd(&counts[tgt[e]], 1);
}

__global__ void chunk_sum_kernel(const int* __restrict__ counts,
                                 int* __restrict__ chunk_sums, int N) {
  __shared__ int red[256];
  int b = blockIdx.x, t = threadIdx.x;
  int base = b * 1024 + t * 4;
  int s = 0;
#pragma unroll
  for (int j = 0; j < 4; ++j) s += (base + j < N) ? counts[base + j] : 0;
  red[t] = s;
  __syncthreads();
  for (int off = 128; off > 0; off >>= 1) {
    if (t < off) red[t] += red[t + off];
    __syncthreads();
  }
  if (t == 0) chunk_sums[b] = red[0];
}

// scan_block with inline chunk-prefix (merges old scan_chunks): wave 0 of
// each block reduces chunk_sums[0..b-1] (nch <= 64).
__global__ void scan_block_kernel(const int* __restrict__ counts,
                                  const int* __restrict__ chunk_sums,
                                  int* __restrict__ offsets,
                                  int* __restrict__ cursor, int N, int E) {
  __shared__ int part[256];
  __shared__ int chunk_base_sh;
  int b = blockIdx.x, t = threadIdx.x;
  if (t < 64) {
    int v = (t < b) ? chunk_sums[t] : 0;
#pragma unroll
    for (int off = 32; off > 0; off >>= 1) v += __shfl_down(v, off);
    if (t == 0) chunk_base_sh = v;
  }
  int base = b * 1024 + t * 4;
  int v[4];
#pragma unroll
  for (int j = 0; j < 4; ++j) v[j] = (base + j < N) ? counts[base + j] : 0;
  int local = v[0] + v[1] + v[2] + v[3];
  part[t] = local;
  __syncthreads();
  for (int off = 1; off < 256; off <<= 1) {
    int x = 0;
    if (t >= off) x = part[t - off];
    __syncthreads();
    if (t >= off) part[t] += x;
    __syncthreads();
  }
  int run = chunk_base_sh + (part[t] - local);
#pragma unroll
  for (int j = 0; j < 4; ++j) {
    if (base + j < N) {
      offsets[base + j] = run;
      cursor[base + j] = run;
      run += v[j];
    }
  }
  if (b == 0 && t == 0) offsets[N] = E;
}

// ---------------------------------------------------------------------------
// Fused edge geometry + CSR scatter (unchanged).
// ---------------------------------------------------------------------------
__global__ void edge_geom_kernel(const float* __restrict__ pos,
                                 const int* __restrict__ src,
                                 const int* __restrict__ tgt,
                                 int* __restrict__ cursor,
                                 float4* __restrict__ dir4_s,
                                 uint_t* __restrict__ rbh_s,
                                 int* __restrict__ src_s, int E) {
  int e = blockIdx.x * 256 + threadIdx.x;
  if (e >= E) return;
  const int sn = src[e];
  const int tn = tgt[e];
  const float rx = pos[tn * 3 + 0] - pos[sn * 3 + 0];
  const float ry = pos[tn * 3 + 1] - pos[sn * 3 + 1];
  const float rz = pos[tn * 3 + 2] - pos[sn * 3 + 2];
  const float dist = sqrtf(rx * rx + ry * ry + rz * rz);
  const float inv = 1.0f / dist;

  const float ang = dist * (PI_F / CUT_OFF_F);
  float s1, c1;
  sincosf(ang, &s1, &c1);
  float sk = s1, ck = c1;
  float rb[NUM_RBF];
  rb[0] = s1 * inv;
#pragma unroll
  for (int r = 1; r < NUM_RBF; ++r) {
    float sn2 = sk * c1 + ck * s1;
    ck = ck * c1 - sk * s1;
    sk = sn2;
    rb[r] = sk * inv;
  }

  const int p = atomicAdd(&cursor[tn], 1);
  dir4_s[p] = make_float4(rx * inv, ry * inv, rz * inv, dist);
  src_s[p] = sn;
  uint_t us[10];
#pragma unroll
  for (int q = 0; q < 10; ++q) us[q] = pack2h(rb[2 * q], rb[2 * q + 1]);
  uint_t* o = rbh_s + (size_t)p * 12;
  *reinterpret_cast<uint4*>(o) = make_uint4(us[0], us[1], us[2], us[3]);
  *reinterpret_cast<uint4*>(o + 4) = make_uint4(us[4], us[5], us[6], us[7]);
  *reinterpret_cast<uint2*>(o + 8) = make_uint2(us[8], us[9]);
}

// ---------------------------------------------------------------------------
// Node gather. Wave-uniform edge streams (rbf/dir) accessed via
// readfirstlane-uniform index so the compiler can emit scalar loads
// (s_load into SGPRs, fdot2 with SGPR operand); merged gather stays
// per-lane vector. shfl-broadcast src, x2 ILP.
// ---------------------------------------------------------------------------
#define NODES_PER_BLOCK 8

__device__ __forceinline__ float cutoff_f(float x) {
  return (x < CUT_OFF_F) ? 0.5f * (1.0f + __cosf(x * (PI_F / CUT_OFF_F))) : 0.f;
}

struct EdgeData {
  float4 dir;
  uint_t rbu[10];
  uint_t su[3];
};

__device__ __forceinline__ void load_edge(int idx, int sn, int d,
                                          const uint_t* __restrict__ merged,
                                          const float4* __restrict__ dir4_s,
                                          const uint_t* __restrict__ rbh_s,
                                          EdgeData& ed) {
  ed.dir = dir4_s[idx];
  const uint_t* o = rbh_s + (size_t)idx * 12;
  uint4 u0 = *reinterpret_cast<const uint4*>(o);
  uint4 u1 = *reinterpret_cast<const uint4*>(o + 4);
  uint2 u2 = *reinterpret_cast<const uint2*>(o + 8);
  ed.rbu[0] = u0.x; ed.rbu[1] = u0.y; ed.rbu[2] = u0.z; ed.rbu[3] = u0.w;
  ed.rbu[4] = u1.x; ed.rbu[5] = u1.y; ed.rbu[6] = u1.z; ed.rbu[7] = u1.w;
  ed.rbu[8] = u2.x; ed.rbu[9] = u2.y;
  const uint_t* mp = merged + ((size_t)sn * 128 + d) * 3;
  ed.su[0] = mp[0]; ed.su[1] = mp[1]; ed.su[2] = mp[2];
}

__global__ __launch_bounds__(128) void node_kernel(
    const uint_t* __restrict__ merged, const float4* __restrict__ dir4_s,
    const uint_t* __restrict__ rbh_s, const int* __restrict__ src_s,
    const int* __restrict__ offsets, const float* __restrict__ Wr,
    const float* __restrict__ br, float* __restrict__ out, int N, int E) {
  const int d = threadIdx.x;
  const int lane = d & 63;

  h2v wr0h[10], wr1h[10], wr2h[10];
#pragma unroll
  for (int q = 0; q < 10; ++q) {
    h2v w;
    w.x = (_Float16)Wr[(2 * q) * 384 + 3 * d + 0];
    w.y = (_Float16)Wr[(2 * q + 1) * 384 + 3 * d + 0];
    wr0h[q] = w;
    w.x = (_Float16)Wr[(2 * q) * 384 + 3 * d + 1];
    w.y = (_Float16)Wr[(2 * q + 1) * 384 + 3 * d + 1];
    wr1h[q] = w;
    w.x = (_Float16)Wr[(2 * q) * 384 + 3 * d + 2];
    w.y = (_Float16)Wr[(2 * q + 1) * 384 + 3 * d + 2];
    wr2h[q] = w;
  }
  const float br0 = br[3 * d + 0];
  const float br1 = br[3 * d + 1];
  const float br2 = br[3 * d + 2];

  for (int nn = 0; nn < NODES_PER_BLOCK; ++nn) {
    const int n = blockIdx.x * NODES_PER_BLOCK + nn;
    if (n >= N) break;

    const int start = offsets[n];
    const int end = offsets[n + 1];

    float accs = 0.f, av0 = 0.f, av1 = 0.f, av2 = 0.f;

    for (int base = start; base < end; base += 64) {
      const int m = min(64, end - base);
      int ld = base + lane;
      if (ld >= E) ld = E - 1;
      const int sn_l = src_s[ld];

      int i = 0;
      for (; i + 2 <= m; i += 2) {
        const int sn0 = __shfl(sn_l, i);
        const int sn1 = __shfl(sn_l, i + 1);
        // uniform edge index -> SGPR, enabling scalar loads of rbf/dir
        const int i0 = __builtin_amdgcn_readfirstlane(base + i);
        EdgeData e0, e1;
        load_edge(i0, sn0, d, merged, dir4_s, rbh_s, e0);
        load_edge(i0 + 1, sn1, d, merged, dir4_s, rbh_s, e1);

#pragma unroll
        for (int u = 0; u < 2; ++u) {
          const EdgeData& ed = (u == 0) ? e0 : e1;
          float f0 = br0, f1 = br1, f2 = br2;
#pragma unroll
          for (int q = 0; q < 10; ++q) {
            h2v r = u2h2(ed.rbu[q]);
            f0 = fdot2f(r, wr0h[q], f0);
            f1 = fdot2f(r, wr1h[q], f1);
            f2 = fdot2f(r, wr2h[q], f2);
          }
          f0 = cutoff_f(f0);
          f1 = cutoff_f(f1);
          f2 = cutoff_f(f2);
          const float m0 = h2f_lo(ed.su[0]) * f0;
          const float m1 = h2f_hi(ed.su[0]) * f1;
          const float m2 = h2f_lo(ed.su[1]) * f2;
          accs += m0;
          av0 += m2 * ed.dir.x + m1 * h2f_hi(ed.su[1]);
          av1 += m2 * ed.dir.y + m1 * h2f_lo(ed.su[2]);
          av2 += m2 * ed.dir.z + m1 * h2f_hi(ed.su[2]);
        }
      }
      if (i < m) {
        const int sn0 = __shfl(sn_l, i);
        const int i0 = __builtin_amdgcn_readfirstlane(base + i);
        EdgeData e0;
        load_edge(i0, sn0, d, merged, dir4_s, rbh_s, e0);
        float f0 = br0, f1 = br1, f2 = br2;
#pragma unroll
        for (int q = 0; q < 10; ++q) {
          h2v r = u2h2(e0.rbu[q]);
          f0 = fdot2f(r, wr0h[q], f0);
          f1 = fdot2f(r, wr1h[q], f1);
          f2 = fdot2f(r, wr2h[q], f2);
        }
        f0 = cutoff_f(f0);
        f1 = cutoff_f(f1);
        f2 = cutoff_f(f2);
        const float m0 = h2f_lo(e0.su[0]) * f0;
        const float m1 = h2f_hi(e0.su[0]) * f1;
        const float m2 = h2f_lo(e0.su[1]) * f2;
        accs += m0;
        av0 += m2 * e0.dir.x + m1 * h2f_hi(e0.su[1]);
        av1 += m2 * e0.dir.y + m1 * h2f_lo(e0.su[2]);
        av2 += m2 * e0.dir.z + m1 * h2f_hi(e0.su[2]);
      }
    }

    out[(size_t)n * 384 + 3 * d + 0] = av0;
    out[(size_t)n * 384 + 3 * d + 1] = av1;
    out[(size_t)n * 384 + 3 * d + 2] = av2;
    out[(size_t)N * 384 + (size_t)n * 128 + d] = accs;
  }
}

// ---------------------------------------------------------------------------
extern "C" void kernel_launch(void* const* d_in, const int* in_sizes, int n_in,
                              void* d_out, int out_size, void* d_ws,
                              size_t ws_size, hipStream_t stream) {
  const float* vf  = (const float*)d_in[0];   // [N,128,3]
  const float* X   = (const float*)d_in[1];   // [N,128]
  const float* pos = (const float*)d_in[2];   // [N,3]
  const int* ei    = (const int*)d_in[3];     // [2,E]
  const float* W1  = (const float*)d_in[4];
  const float* b1  = (const float*)d_in[5];
  const float* W2  = (const float*)d_in[6];
  const float* b2  = (const float*)d_in[7];
  const float* Wr  = (const float*)d_in[8];
  const float* br  = (const float*)d_in[9];

  const int N = in_sizes[1] / D_DIM;
  const int E = in_sizes[3] / 2;
  const int* srcI = ei;
  const int* tgtI = ei + E;
  float* out = (float*)d_out;

  // workspace layout (16B-aligned chunks first)
  char* w = (char*)d_ws;
  float4* dir4_s = (float4*)w;  w += (size_t)E * sizeof(float4);
  uint_t* rbh_s  = (uint_t*)w;  w += (size_t)E * 12 * sizeof(uint_t);
  uint_t* merged = (uint_t*)w;  w += (size_t)N * 128 * 3 * sizeof(uint_t);
  int* src_s     = (int*)w;     w += (size_t)E * sizeof(int);
  int* counts    = (int*)w;     w += (size_t)N * sizeof(int);
  int* offsets   = (int*)w;     w += (size_t)(N + 1) * sizeof(int);
  int* cursor    = (int*)w;     w += (size_t)N * sizeof(int);
  int* chunks    = (int*)w;     w += 64 * sizeof(int);

  const int nch = (N + 1023) / 1024;  // 49 for N=50000 (<= 64 required)

  proj_kernel<<<(N + 63) / 64, 256, 0, stream>>>(X, W1, b1, W2, b2, vf, merged,
                                                 counts, N);
  hist_kernel<<<(E + 255) / 256, 256, 0, stream>>>(tgtI, counts, E);
  chunk_sum_kernel<<<nch, 256, 0, stream>>>(counts, chunks, N);
  scan_block_kernel<<<nch, 256, 0, stream>>>(counts, chunks, offsets, cursor,
                                             N, E);
  edge_geom_kernel<<<(E + 255) / 256, 256, 0, stream>>>(pos, srcI, tgtI, cursor,
                                                        dir4_s, rbh_s, src_s, E);
  node_kernel<<<(N + NODES_PER_BLOCK - 1) / NODES_PER_BLOCK, 128, 0, stream>>>(
      merged, dir4_s, rbh_s, src_s, offsets, Wr, br, out, N, E);
}

// Round 12
// 285.536 us; speedup vs baseline: 1.2386x; 1.0407x over previous
//
#include <hip/hip_runtime.h>
#include <hip/hip_fp16.h>
#include <math.h>
#include <stddef.h>

#define D_DIM 128
#define NUM_RBF 20
typedef unsigned short ushort_t;
typedef unsigned int uint_t;
typedef _Float16 h2v __attribute__((ext_vector_type(2)));
typedef _Float16 half8_t __attribute__((ext_vector_type(8)));
typedef float float4_t __attribute__((ext_vector_type(4)));
constexpr float PI_F = 3.14159265358979323846f;
constexpr float CUT_OFF_F = 5.0f;
constexpr float SILU_SCALE_F = 1.0f / 0.6f;

__device__ __forceinline__ uint_t pack2h(float a, float b) {
  __half2 h2 = __floats2half2_rn(a, b);
  return *reinterpret_cast<uint_t*>(&h2);
}
__device__ __forceinline__ float h2f(ushort_t u) {
  __half h = __ushort_as_half(u);
  return __half2float(h);
}
__device__ __forceinline__ float h2f_lo(uint_t u) { return h2f((ushort_t)(u & 0xffffu)); }
__device__ __forceinline__ float h2f_hi(uint_t u) { return h2f((ushort_t)(u >> 16)); }
__device__ __forceinline__ h2v u2h2(uint_t u) {
  h2v r;
  __builtin_memcpy(&r, &u, 4);
  return r;
}

#if defined(__has_builtin)
#if __has_builtin(__builtin_amdgcn_fdot2)
#define HAVE_FDOT2 1
#endif
#endif

__device__ __forceinline__ float fdot2f(h2v a, h2v b, float c) {
#ifdef HAVE_FDOT2
  return __builtin_amdgcn_fdot2(a, b, c, false);
#else
  return c + (float)a.x * (float)b.x + (float)a.y * (float)b.y;
#endif
}

// 64B per-edge record: all wave-uniform data in one scalar-loadable block.
struct __align__(16) EdgeRec {
  uint_t rb[10];   // rbf packed fp16x2
  uint_t src;      // source node
  float dx, dy, dz;
  uint_t pad[2];
};

// ---------------------------------------------------------------------------
// MFMA node projection + merged-buffer build (R10-verified) + counts zeroing.
// ---------------------------------------------------------------------------
__device__ __forceinline__ void stage_wt(const float* __restrict__ W,
                                         _Float16* __restrict__ Wt, int t,
                                         int f4stride, int f4base) {
  const float4* Wv = reinterpret_cast<const float4*>(W);
#pragma unroll
  for (int i = 0; i < 8; ++i) {
    int pid = t + i * 256;            // 0..2047: 64 k-pairs x 32 n-float4s
    int k = (pid >> 5) * 2;
    int nf = pid & 31;
    float4 a = Wv[(size_t)k * f4stride + f4base + nf];
    float4 b = Wv[(size_t)(k + 1) * f4stride + f4base + nf];
    const float av[4] = {a.x, a.y, a.z, a.w};
    const float bv[4] = {b.x, b.y, b.z, b.w};
    const int n0 = nf * 4;
#pragma unroll
    for (int j = 0; j < 4; ++j)
      *reinterpret_cast<uint_t*>(&Wt[(n0 + j) * 136 + k]) =
          pack2h(av[j], bv[j]);
  }
}

__global__ __launch_bounds__(256) void proj_kernel(
    const float* __restrict__ X, const float* __restrict__ W1,
    const float* __restrict__ b1, const float* __restrict__ W2,
    const float* __restrict__ b2, const float* __restrict__ vf,
    uint_t* __restrict__ merged, int* __restrict__ counts, int N) {
  __shared__ alignas(16) _Float16 smem[26112];  // Xs[64*136] + Wt[128*136]
  _Float16* Xs = smem;
  _Float16* Wt = smem + 8704;

  const int t = threadIdx.x;
  const int w = t >> 6;        // wave 0..3
  const int l = t & 63;        // lane
  const int nb = blockIdx.x * 64;

  // ---- fold-in: zero the CSR counts array ----
  {
    int z = blockIdx.x * 256 + t;
    if (z < N) counts[z] = 0;
  }

  // ---- stage X tile: [64][128] fp32 -> Xs[64][136] fp16 ----
  {
    const float4* Xv = reinterpret_cast<const float4*>(X);
#pragma unroll
    for (int i = 0; i < 8; ++i) {
      int g = t + i * 256;            // 0..2047
      int row = g >> 5, k0 = (g & 31) * 4;
      int node = nb + row;
      float4 v = (node < N) ? Xv[(size_t)nb * 32 + g]
                            : make_float4(0.f, 0.f, 0.f, 0.f);
      uint_t* dst = reinterpret_cast<uint_t*>(&Xs[row * 136 + k0]);
      dst[0] = pack2h(v.x, v.y);
      dst[1] = pack2h(v.z, v.w);
    }
  }
  stage_wt(W1, Wt, t, 32, 0);
  __syncthreads();

  const int arow = w * 16 + (l & 15);
  const int koff = (l >> 4) * 8;
  const int bcol = l & 15;

  // ---- phase 1: H = X @ W1 ----
  half8_t af[4];
#pragma unroll
  for (int s = 0; s < 4; ++s)
    af[s] = *reinterpret_cast<const half8_t*>(&Xs[arow * 136 + s * 32 + koff]);

  float4_t acc[8];
#pragma unroll
  for (int c = 0; c < 8; ++c) {
    float4_t a = {0.f, 0.f, 0.f, 0.f};
#pragma unroll
    for (int s = 0; s < 4; ++s) {
      half8_t bf = *reinterpret_cast<const half8_t*>(
          &Wt[(c * 16 + bcol) * 136 + s * 32 + koff]);
      a = __builtin_amdgcn_mfma_f32_16x16x32_f16(af[s], bf, a, 0, 0, 0);
    }
    acc[c] = a;
  }

  __syncthreads();  // all Xs/Wt reads done before overwrite

  // ---- bias + scaled-silu -> H (fp16) into Xs; stage W2 chunk 0 ----
#pragma unroll
  for (int c = 0; c < 8; ++c) {
    const int col = c * 16 + bcol;
    const float bv = b1[col];
#pragma unroll
    for (int r = 0; r < 4; ++r) {
      const int row = w * 16 + (l >> 4) * 4 + r;
      float hv = acc[c][r] + bv;
      hv = hv * SILU_SCALE_F / (1.0f + expf(-hv));
      Xs[row * 136 + col] = (_Float16)hv;
    }
  }
  stage_wt(W2, Wt, t, 96, 0);
  __syncthreads();

  // ---- phase 2: S = H @ W2 + b2, 3 col-chunks of 128; results in regs ----
  half8_t ha[4];
#pragma unroll
  for (int s = 0; s < 4; ++s)
    ha[s] = *reinterpret_cast<const half8_t*>(&Xs[arow * 136 + s * 32 + koff]);

  uint_t pk[3][8][2];   // packed fp16 results; fully static indexing
#pragma unroll
  for (int cn = 0; cn < 3; ++cn) {
    if (cn > 0) {
      __syncthreads();                // prev chunk's Wt reads done
      stage_wt(W2, Wt, t, 96, cn * 32);
      __syncthreads();
    }
#pragma unroll
    for (int c = 0; c < 8; ++c) {
      float4_t a = {0.f, 0.f, 0.f, 0.f};
#pragma unroll
      for (int s = 0; s < 4; ++s) {
        half8_t bf = *reinterpret_cast<const half8_t*>(
            &Wt[(c * 16 + bcol) * 136 + s * 32 + koff]);
        a = __builtin_amdgcn_mfma_f32_16x16x32_f16(ha[s], bf, a, 0, 0, 0);
      }
      const float bv = b2[cn * 128 + c * 16 + bcol];
      pk[cn][c][0] = pack2h(a[0] + bv, a[1] + bv);
      pk[cn][c][1] = pack2h(a[2] + bv, a[3] + bv);
    }
  }

  // ---- bounce S to LDS natural [64][392] ----
  __syncthreads();                    // all Wt reads done; smem reusable
  ushort_t* sh = reinterpret_cast<ushort_t*>(smem);
  {
    const int rbase = w * 16 + (l >> 4) * 4;
#pragma unroll
    for (int cn = 0; cn < 3; ++cn)
#pragma unroll
      for (int c = 0; c < 8; ++c) {
        const int gcol = cn * 128 + c * 16 + bcol;
        sh[(rbase + 0) * 392 + gcol] = (ushort_t)(pk[cn][c][0] & 0xffffu);
        sh[(rbase + 1) * 392 + gcol] = (ushort_t)(pk[cn][c][0] >> 16);
        sh[(rbase + 2) * 392 + gcol] = (ushort_t)(pk[cn][c][1] & 0xffffu);
        sh[(rbase + 3) * 392 + gcol] = (ushort_t)(pk[cn][c][1] >> 16);
      }
  }
  __syncthreads();

  // ---- merged build: stream vf, write {s|s, s|v, v|v} per (node,chan) ----
#pragma unroll 4
  for (int k = 0; k < 32; ++k) {
    const int P = k * 256 + t;        // 0..8191
    const int ln = P >> 7;            // local node 0..63
    const int chan = P & 127;
    const int node = nb + ln;
    if (node < N) {
      const ushort_t* sp = &sh[ln * 392 + 3 * chan];
      const float* vp = vf + ((size_t)node * 128 + chan) * 3;
      uint_t* mp = merged + ((size_t)node * 128 + chan) * 3;
      mp[0] = (uint_t)sp[0] | ((uint_t)sp[1] << 16);
      mp[1] = (uint_t)sp[2] |
              ((uint_t)__half_as_ushort(__float2half_rn(vp[0])) << 16);
      mp[2] = pack2h(vp[1], vp[2]);
    }
  }
}

// ---------------------------------------------------------------------------
// CSR build
// ---------------------------------------------------------------------------
__global__ void hist_kernel(const int* __restrict__ tgt, int* __restrict__ counts,
                            int E) {
  int e = blockIdx.x * 256 + threadIdx.x;
  if (e < E) atomicAdd(&counts[tgt[e]], 1);
}

__global__ void chunk_sum_kernel(const int* __restrict__ counts,
                                 int* __restrict__ chunk_sums, int N) {
  __shared__ int red[256];
  int b = blockIdx.x, t = threadIdx.x;
  int base = b * 1024 + t * 4;
  int s = 0;
#pragma unroll
  for (int j = 0; j < 4; ++j) s += (base + j < N) ? counts[base + j] : 0;
  red[t] = s;
  __syncthreads();
  for (int off = 128; off > 0; off >>= 1) {
    if (t < off) red[t] += red[t + off];
    __syncthreads();
  }
  if (t == 0) chunk_sums[b] = red[0];
}

__global__ void scan_block_kernel(const int* __restrict__ counts,
                                  const int* __restrict__ chunk_sums,
                                  int* __restrict__ offsets,
                                  int* __restrict__ cursor, int N, int E) {
  __shared__ int part[256];
  __shared__ int chunk_base_sh;
  int b = blockIdx.x, t = threadIdx.x;
  if (t < 64) {
    int v = (t < b) ? chunk_sums[t] : 0;
#pragma unroll
    for (int off = 32; off > 0; off >>= 1) v += __shfl_down(v, off);
    if (t == 0) chunk_base_sh = v;
  }
  int base = b * 1024 + t * 4;
  int v[4];
#pragma unroll
  for (int j = 0; j < 4; ++j) v[j] = (base + j < N) ? counts[base + j] : 0;
  int local = v[0] + v[1] + v[2] + v[3];
  part[t] = local;
  __syncthreads();
  for (int off = 1; off < 256; off <<= 1) {
    int x = 0;
    if (t >= off) x = part[t - off];
    __syncthreads();
    if (t >= off) part[t] += x;
    __syncthreads();
  }
  int run = chunk_base_sh + (part[t] - local);
#pragma unroll
  for (int j = 0; j < 4; ++j) {
    if (base + j < N) {
      offsets[base + j] = run;
      cursor[base + j] = run;
      run += v[j];
    }
  }
  if (b == 0 && t == 0) offsets[N] = E;
}

// ---------------------------------------------------------------------------
// Fused edge geometry + CSR scatter into 64B EdgeRec records.
// ---------------------------------------------------------------------------
__global__ void edge_geom_kernel(const float* __restrict__ pos,
                                 const int* __restrict__ src,
                                 const int* __restrict__ tgt,
                                 int* __restrict__ cursor,
                                 EdgeRec* __restrict__ recs, int E) {
  int e = blockIdx.x * 256 + threadIdx.x;
  if (e >= E) return;
  const int sn = src[e];
  const int tn = tgt[e];
  const float rx = pos[tn * 3 + 0] - pos[sn * 3 + 0];
  const float ry = pos[tn * 3 + 1] - pos[sn * 3 + 1];
  const float rz = pos[tn * 3 + 2] - pos[sn * 3 + 2];
  const float dist = sqrtf(rx * rx + ry * ry + rz * rz);
  const float inv = 1.0f / dist;

  const float ang = dist * (PI_F / CUT_OFF_F);
  float s1, c1;
  sincosf(ang, &s1, &c1);
  float sk = s1, ck = c1;
  float rb[NUM_RBF];
  rb[0] = s1 * inv;
#pragma unroll
  for (int r = 1; r < NUM_RBF; ++r) {
    float sn2 = sk * c1 + ck * s1;
    ck = ck * c1 - sk * s1;
    sk = sn2;
    rb[r] = sk * inv;
  }

  const int p = atomicAdd(&cursor[tn], 1);
  uint_t us[10];
#pragma unroll
  for (int q = 0; q < 10; ++q) us[q] = pack2h(rb[2 * q], rb[2 * q + 1]);
  uint_t* o = reinterpret_cast<uint_t*>(&recs[p]);
  *reinterpret_cast<uint4*>(o) = make_uint4(us[0], us[1], us[2], us[3]);
  *reinterpret_cast<uint4*>(o + 4) = make_uint4(us[4], us[5], us[6], us[7]);
  *reinterpret_cast<uint4*>(o + 8) =
      make_uint4(us[8], us[9], (uint_t)sn, __float_as_uint(rx * inv));
  *reinterpret_cast<uint4*>(o + 12) =
      make_uint4(__float_as_uint(ry * inv), __float_as_uint(rz * inv), 0u, 0u);
}

// ---------------------------------------------------------------------------
// Node gather. Per edge: ONE wave-uniform 64B record (scalar s_load path:
// rbf, src, dir all land in SGPRs) + 3 per-lane merged dwords. Plain
// uniform loop over the CSR range, x2 unroll for load/compute overlap.
// ---------------------------------------------------------------------------
#define NODES_PER_BLOCK 8

__device__ __forceinline__ float cutoff_f(float x) {
  return (x < CUT_OFF_F) ? 0.5f * (1.0f + __cosf(x * (PI_F / CUT_OFF_F))) : 0.f;
}

__global__ __launch_bounds__(128) void node_kernel(
    const uint_t* __restrict__ merged, const EdgeRec* __restrict__ recs,
    const int* __restrict__ offsets, const float* __restrict__ Wr,
    const float* __restrict__ br, float* __restrict__ out, int N) {
  const int d = threadIdx.x;

  h2v wr0h[10], wr1h[10], wr2h[10];
#pragma unroll
  for (int q = 0; q < 10; ++q) {
    h2v w;
    w.x = (_Float16)Wr[(2 * q) * 384 + 3 * d + 0];
    w.y = (_Float16)Wr[(2 * q + 1) * 384 + 3 * d + 0];
    wr0h[q] = w;
    w.x = (_Float16)Wr[(2 * q) * 384 + 3 * d + 1];
    w.y = (_Float16)Wr[(2 * q + 1) * 384 + 3 * d + 1];
    wr1h[q] = w;
    w.x = (_Float16)Wr[(2 * q) * 384 + 3 * d + 2];
    w.y = (_Float16)Wr[(2 * q + 1) * 384 + 3 * d + 2];
    wr2h[q] = w;
  }
  const float br0 = br[3 * d + 0];
  const float br1 = br[3 * d + 1];
  const float br2 = br[3 * d + 2];

  for (int nn = 0; nn < NODES_PER_BLOCK; ++nn) {
    const int n = blockIdx.x * NODES_PER_BLOCK + nn;
    if (n >= N) break;

    const int start = offsets[n];
    const int end = offsets[n + 1];

    float accs = 0.f, av0 = 0.f, av1 = 0.f, av2 = 0.f;

    int i = start;
    for (; i + 2 <= end; i += 2) {
      const int i0 = __builtin_amdgcn_readfirstlane(i);
      const EdgeRec& eA = recs[i0];
      const EdgeRec& eB = recs[i0 + 1];
      const int snA = (int)eA.src;
      const int snB = (int)eB.src;
      const uint_t* mpA = merged + ((size_t)snA * 128 + d) * 3;
      const uint_t* mpB = merged + ((size_t)snB * 128 + d) * 3;
      const uint_t suA0 = mpA[0], suA1 = mpA[1], suA2 = mpA[2];
      const uint_t suB0 = mpB[0], suB1 = mpB[1], suB2 = mpB[2];

      {
        float f0 = br0, f1 = br1, f2 = br2;
#pragma unroll
        for (int q = 0; q < 10; ++q) {
          h2v r = u2h2(eA.rb[q]);
          f0 = fdot2f(r, wr0h[q], f0);
          f1 = fdot2f(r, wr1h[q], f1);
          f2 = fdot2f(r, wr2h[q], f2);
        }
        f0 = cutoff_f(f0);
        f1 = cutoff_f(f1);
        f2 = cutoff_f(f2);
        const float m0 = h2f_lo(suA0) * f0;
        const float m1 = h2f_hi(suA0) * f1;
        const float m2 = h2f_lo(suA1) * f2;
        accs += m0;
        av0 += m2 * eA.dx + m1 * h2f_hi(suA1);
        av1 += m2 * eA.dy + m1 * h2f_lo(suA2);
        av2 += m2 * eA.dz + m1 * h2f_hi(suA2);
      }
      {
        float f0 = br0, f1 = br1, f2 = br2;
#pragma unroll
        for (int q = 0; q < 10; ++q) {
          h2v r = u2h2(eB.rb[q]);
          f0 = fdot2f(r, wr0h[q], f0);
          f1 = fdot2f(r, wr1h[q], f1);
          f2 = fdot2f(r, wr2h[q], f2);
        }
        f0 = cutoff_f(f0);
        f1 = cutoff_f(f1);
        f2 = cutoff_f(f2);
        const float m0 = h2f_lo(suB0) * f0;
        const float m1 = h2f_hi(suB0) * f1;
        const float m2 = h2f_lo(suB1) * f2;
        accs += m0;
        av0 += m2 * eB.dx + m1 * h2f_hi(suB1);
        av1 += m2 * eB.dy + m1 * h2f_lo(suB2);
        av2 += m2 * eB.dz + m1 * h2f_hi(suB2);
      }
    }
    if (i < end) {
      const int i0 = __builtin_amdgcn_readfirstlane(i);
      const EdgeRec& eA = recs[i0];
      const int snA = (int)eA.src;
      const uint_t* mpA = merged + ((size_t)snA * 128 + d) * 3;
      const uint_t suA0 = mpA[0], suA1 = mpA[1], suA2 = mpA[2];
      float f0 = br0, f1 = br1, f2 = br2;
#pragma unroll
      for (int q = 0; q < 10; ++q) {
        h2v r = u2h2(eA.rb[q]);
        f0 = fdot2f(r, wr0h[q], f0);
        f1 = fdot2f(r, wr1h[q], f1);
        f2 = fdot2f(r, wr2h[q], f2);
      }
      f0 = cutoff_f(f0);
      f1 = cutoff_f(f1);
      f2 = cutoff_f(f2);
      const float m0 = h2f_lo(suA0) * f0;
      const float m1 = h2f_hi(suA0) * f1;
      const float m2 = h2f_lo(suA1) * f2;
      accs += m0;
      av0 += m2 * eA.dx + m1 * h2f_hi(suA1);
      av1 += m2 * eA.dy + m1 * h2f_lo(suA2);
      av2 += m2 * eA.dz + m1 * h2f_hi(suA2);
    }

    out[(size_t)n * 384 + 3 * d + 0] = av0;
    out[(size_t)n * 384 + 3 * d + 1] = av1;
    out[(size_t)n * 384 + 3 * d + 2] = av2;
    out[(size_t)N * 384 + (size_t)n * 128 + d] = accs;
  }
}

// ---------------------------------------------------------------------------
extern "C" void kernel_launch(void* const* d_in, const int* in_sizes, int n_in,
                              void* d_out, int out_size, void* d_ws,
                              size_t ws_size, hipStream_t stream) {
  const float* vf  = (const float*)d_in[0];   // [N,128,3]
  const float* X   = (const float*)d_in[1];   // [N,128]
  const float* pos = (const float*)d_in[2];   // [N,3]
  const int* ei    = (const int*)d_in[3];     // [2,E]
  const float* W1  = (const float*)d_in[4];
  const float* b1  = (const float*)d_in[5];
  const float* W2  = (const float*)d_in[6];
  const float* b2  = (const float*)d_in[7];
  const float* Wr  = (const float*)d_in[8];
  const float* br  = (const float*)d_in[9];

  const int N = in_sizes[1] / D_DIM;
  const int E = in_sizes[3] / 2;
  const int* srcI = ei;
  const int* tgtI = ei + E;
  float* out = (float*)d_out;

  // workspace layout (16B-aligned chunks first)
  char* w = (char*)d_ws;
  EdgeRec* recs  = (EdgeRec*)w; w += (size_t)E * sizeof(EdgeRec);
  uint_t* merged = (uint_t*)w;  w += (size_t)N * 128 * 3 * sizeof(uint_t);
  int* counts    = (int*)w;     w += (size_t)N * sizeof(int);
  int* offsets   = (int*)w;     w += (size_t)(N + 1) * sizeof(int);
  int* cursor    = (int*)w;     w += (size_t)N * sizeof(int);
  int* chunks    = (int*)w;     w += 64 * sizeof(int);

  const int nch = (N + 1023) / 1024;  // 49 for N=50000 (<= 64 required)

  proj_kernel<<<(N + 63) / 64, 256, 0, stream>>>(X, W1, b1, W2, b2, vf, merged,
                                                 counts, N);
  hist_kernel<<<(E + 255) / 256, 256, 0, stream>>>(tgtI, counts, E);
  chunk_sum_kernel<<<nch, 256, 0, stream>>>(counts, chunks, N);
  scan_block_kernel<<<nch, 256, 0, stream>>>(counts, chunks, offsets, cursor,
                                             N, E);
  edge_geom_kernel<<<(E + 255) / 256, 256, 0, stream>>>(pos, srcI, tgtI, cursor,
                                                        recs, E);
  node_kernel<<<(N + NODES_PER_BLOCK - 1) / NODES_PER_BLOCK, 128, 0, stream>>>(
      merged, recs, offsets, Wr, br, out, N);
}

// Round 13
// 281.648 us; speedup vs baseline: 1.2557x; 1.0138x over previous
//
#include <hip/hip_runtime.h>
#include <hip/hip_fp16.h>
#include <math.h>
#include <stddef.h>

#define D_DIM 128
#define NUM_RBF 20
typedef unsigned short ushort_t;
typedef unsigned int uint_t;
typedef _Float16 h2v __attribute__((ext_vector_type(2)));
typedef _Float16 half8_t __attribute__((ext_vector_type(8)));
typedef float float4_t __attribute__((ext_vector_type(4)));
constexpr float PI_F = 3.14159265358979323846f;
constexpr float CUT_OFF_F = 5.0f;
constexpr float SILU_SCALE_F = 1.0f / 0.6f;

__device__ __forceinline__ uint_t pack2h(float a, float b) {
  __half2 h2 = __floats2half2_rn(a, b);
  return *reinterpret_cast<uint_t*>(&h2);
}
__device__ __forceinline__ float h2f(ushort_t u) {
  __half h = __ushort_as_half(u);
  return __half2float(h);
}
__device__ __forceinline__ float h2f_lo(uint_t u) { return h2f((ushort_t)(u & 0xffffu)); }
__device__ __forceinline__ float h2f_hi(uint_t u) { return h2f((ushort_t)(u >> 16)); }
__device__ __forceinline__ h2v u2h2(uint_t u) {
  h2v r;
  __builtin_memcpy(&r, &u, 4);
  return r;
}

#if defined(__has_builtin)
#if __has_builtin(__builtin_amdgcn_fdot2)
#define HAVE_FDOT2 1
#endif
#endif

__device__ __forceinline__ float fdot2f(h2v a, h2v b, float c) {
#ifdef HAVE_FDOT2
  return __builtin_amdgcn_fdot2(a, b, c, false);
#else
  return c + (float)a.x * (float)b.x + (float)a.y * (float)b.y;
#endif
}

// 64B per-edge record: all wave-uniform data in one scalar-loadable block.
struct __align__(16) EdgeRec {
  uint_t rb[10];   // rbf packed fp16x2
  uint_t src;      // source node
  float dx, dy, dz;
  uint_t pad[2];
};

// ---------------------------------------------------------------------------
// MFMA node projection + merged-buffer build + counts zeroing.
// R13: merged-build phase vectorized 4 chans/work-item (uint2 LDS reads,
// float4 vf loads, uint4 merged stores) — VMEM inst 192 -> 48 per thread.
// ---------------------------------------------------------------------------
__device__ __forceinline__ void stage_wt(const float* __restrict__ W,
                                         _Float16* __restrict__ Wt, int t,
                                         int f4stride, int f4base) {
  const float4* Wv = reinterpret_cast<const float4*>(W);
#pragma unroll
  for (int i = 0; i < 8; ++i) {
    int pid = t + i * 256;            // 0..2047: 64 k-pairs x 32 n-float4s
    int k = (pid >> 5) * 2;
    int nf = pid & 31;
    float4 a = Wv[(size_t)k * f4stride + f4base + nf];
    float4 b = Wv[(size_t)(k + 1) * f4stride + f4base + nf];
    const float av[4] = {a.x, a.y, a.z, a.w};
    const float bv[4] = {b.x, b.y, b.z, b.w};
    const int n0 = nf * 4;
#pragma unroll
    for (int j = 0; j < 4; ++j)
      *reinterpret_cast<uint_t*>(&Wt[(n0 + j) * 136 + k]) =
          pack2h(av[j], bv[j]);
  }
}

__global__ __launch_bounds__(256) void proj_kernel(
    const float* __restrict__ X, const float* __restrict__ W1,
    const float* __restrict__ b1, const float* __restrict__ W2,
    const float* __restrict__ b2, const float* __restrict__ vf,
    uint_t* __restrict__ merged, int* __restrict__ counts, int N) {
  __shared__ alignas(16) _Float16 smem[26112];  // Xs[64*136] + Wt[128*136]
  _Float16* Xs = smem;
  _Float16* Wt = smem + 8704;

  const int t = threadIdx.x;
  const int w = t >> 6;        // wave 0..3
  const int l = t & 63;        // lane
  const int nb = blockIdx.x * 64;

  // ---- fold-in: zero the CSR counts array ----
  {
    int z = blockIdx.x * 256 + t;
    if (z < N) counts[z] = 0;
  }

  // ---- stage X tile: [64][128] fp32 -> Xs[64][136] fp16 ----
  {
    const float4* Xv = reinterpret_cast<const float4*>(X);
#pragma unroll
    for (int i = 0; i < 8; ++i) {
      int g = t + i * 256;            // 0..2047
      int row = g >> 5, k0 = (g & 31) * 4;
      int node = nb + row;
      float4 v = (node < N) ? Xv[(size_t)nb * 32 + g]
                            : make_float4(0.f, 0.f, 0.f, 0.f);
      uint_t* dst = reinterpret_cast<uint_t*>(&Xs[row * 136 + k0]);
      dst[0] = pack2h(v.x, v.y);
      dst[1] = pack2h(v.z, v.w);
    }
  }
  stage_wt(W1, Wt, t, 32, 0);
  __syncthreads();

  const int arow = w * 16 + (l & 15);
  const int koff = (l >> 4) * 8;
  const int bcol = l & 15;

  // ---- phase 1: H = X @ W1 ----
  half8_t af[4];
#pragma unroll
  for (int s = 0; s < 4; ++s)
    af[s] = *reinterpret_cast<const half8_t*>(&Xs[arow * 136 + s * 32 + koff]);

  float4_t acc[8];
#pragma unroll
  for (int c = 0; c < 8; ++c) {
    float4_t a = {0.f, 0.f, 0.f, 0.f};
#pragma unroll
    for (int s = 0; s < 4; ++s) {
      half8_t bf = *reinterpret_cast<const half8_t*>(
          &Wt[(c * 16 + bcol) * 136 + s * 32 + koff]);
      a = __builtin_amdgcn_mfma_f32_16x16x32_f16(af[s], bf, a, 0, 0, 0);
    }
    acc[c] = a;
  }

  __syncthreads();  // all Xs/Wt reads done before overwrite

  // ---- bias + scaled-silu -> H (fp16) into Xs; stage W2 chunk 0 ----
#pragma unroll
  for (int c = 0; c < 8; ++c) {
    const int col = c * 16 + bcol;
    const float bv = b1[col];
#pragma unroll
    for (int r = 0; r < 4; ++r) {
      const int row = w * 16 + (l >> 4) * 4 + r;
      float hv = acc[c][r] + bv;
      hv = hv * SILU_SCALE_F / (1.0f + expf(-hv));
      Xs[row * 136 + col] = (_Float16)hv;
    }
  }
  stage_wt(W2, Wt, t, 96, 0);
  __syncthreads();

  // ---- phase 2: S = H @ W2 + b2, 3 col-chunks of 128; results in regs ----
  half8_t ha[4];
#pragma unroll
  for (int s = 0; s < 4; ++s)
    ha[s] = *reinterpret_cast<const half8_t*>(&Xs[arow * 136 + s * 32 + koff]);

  uint_t pk[3][8][2];   // packed fp16 results; fully static indexing
#pragma unroll
  for (int cn = 0; cn < 3; ++cn) {
    if (cn > 0) {
      __syncthreads();                // prev chunk's Wt reads done
      stage_wt(W2, Wt, t, 96, cn * 32);
      __syncthreads();
    }
#pragma unroll
    for (int c = 0; c < 8; ++c) {
      float4_t a = {0.f, 0.f, 0.f, 0.f};
#pragma unroll
      for (int s = 0; s < 4; ++s) {
        half8_t bf = *reinterpret_cast<const half8_t*>(
            &Wt[(c * 16 + bcol) * 136 + s * 32 + koff]);
        a = __builtin_amdgcn_mfma_f32_16x16x32_f16(ha[s], bf, a, 0, 0, 0);
      }
      const float bv = b2[cn * 128 + c * 16 + bcol];
      pk[cn][c][0] = pack2h(a[0] + bv, a[1] + bv);
      pk[cn][c][1] = pack2h(a[2] + bv, a[3] + bv);
    }
  }

  // ---- bounce S to LDS natural [64][392] ----
  __syncthreads();                    // all Wt reads done; smem reusable
  ushort_t* sh = reinterpret_cast<ushort_t*>(smem);
  {
    const int rbase = w * 16 + (l >> 4) * 4;
#pragma unroll
    for (int cn = 0; cn < 3; ++cn)
#pragma unroll
      for (int c = 0; c < 8; ++c) {
        const int gcol = cn * 128 + c * 16 + bcol;
        sh[(rbase + 0) * 392 + gcol] = (ushort_t)(pk[cn][c][0] & 0xffffu);
        sh[(rbase + 1) * 392 + gcol] = (ushort_t)(pk[cn][c][0] >> 16);
        sh[(rbase + 2) * 392 + gcol] = (ushort_t)(pk[cn][c][1] & 0xffffu);
        sh[(rbase + 3) * 392 + gcol] = (ushort_t)(pk[cn][c][1] >> 16);
      }
  }
  __syncthreads();

  // ---- merged build, VECTORIZED: 4 chans per work item ----
  // item (ln, cg=4*jj): LDS 3x uint2 (8B-aligned: 784*ln + 24*jj), vf 3x
  // float4 (16B-aligned: 48*jj), merged 3x uint4.
#pragma unroll
  for (int k = 0; k < 8; ++k) {
    const int P = k * 256 + t;        // 0..2047
    const int ln = P >> 5;            // local node 0..63
    const int cg = (P & 31) * 4;      // chan group base 0,4,..,124
    const int node = nb + ln;
    if (node < N) {
      const ushort_t* sp = &sh[ln * 392 + 3 * cg];
      uint2 sa = *reinterpret_cast<const uint2*>(sp);
      uint2 sb = *reinterpret_cast<const uint2*>(sp + 4);
      uint2 sc = *reinterpret_cast<const uint2*>(sp + 8);
      ushort_t s12[12];
      s12[0] = (ushort_t)(sa.x & 0xffffu);  s12[1] = (ushort_t)(sa.x >> 16);
      s12[2] = (ushort_t)(sa.y & 0xffffu);  s12[3] = (ushort_t)(sa.y >> 16);
      s12[4] = (ushort_t)(sb.x & 0xffffu);  s12[5] = (ushort_t)(sb.x >> 16);
      s12[6] = (ushort_t)(sb.y & 0xffffu);  s12[7] = (ushort_t)(sb.y >> 16);
      s12[8] = (ushort_t)(sc.x & 0xffffu);  s12[9] = (ushort_t)(sc.x >> 16);
      s12[10] = (ushort_t)(sc.y & 0xffffu); s12[11] = (ushort_t)(sc.y >> 16);

      const float4* vp =
          reinterpret_cast<const float4*>(vf + ((size_t)node * 128 + cg) * 3);
      float4 v0 = vp[0], v1 = vp[1], v2 = vp[2];
      float vv[12] = {v0.x, v0.y, v0.z, v0.w, v1.x, v1.y,
                      v1.z, v1.w, v2.x, v2.y, v2.z, v2.w};

      uint_t o[12];
#pragma unroll
      for (int j = 0; j < 4; ++j) {
        o[3 * j + 0] = (uint_t)s12[3 * j] | ((uint_t)s12[3 * j + 1] << 16);
        o[3 * j + 1] =
            (uint_t)s12[3 * j + 2] |
            ((uint_t)__half_as_ushort(__float2half_rn(vv[3 * j])) << 16);
        o[3 * j + 2] = pack2h(vv[3 * j + 1], vv[3 * j + 2]);
      }
      uint_t* mp = merged + ((size_t)node * 128 + cg) * 3;
      *reinterpret_cast<uint4*>(mp) = make_uint4(o[0], o[1], o[2], o[3]);
      *reinterpret_cast<uint4*>(mp + 4) = make_uint4(o[4], o[5], o[6], o[7]);
      *reinterpret_cast<uint4*>(mp + 8) = make_uint4(o[8], o[9], o[10], o[11]);
    }
  }
}

// ---------------------------------------------------------------------------
// CSR build
// ---------------------------------------------------------------------------
__global__ void hist_kernel(const int* __restrict__ tgt, int* __restrict__ counts,
                            int E) {
  int e = blockIdx.x * 256 + threadIdx.x;
  if (e < E) atomicAdd(&counts[tgt[e]], 1);
}

__global__ void chunk_sum_kernel(const int* __restrict__ counts,
                                 int* __restrict__ chunk_sums, int N) {
  __shared__ int red[256];
  int b = blockIdx.x, t = threadIdx.x;
  int base = b * 1024 + t * 4;
  int s = 0;
#pragma unroll
  for (int j = 0; j < 4; ++j) s += (base + j < N) ? counts[base + j] : 0;
  red[t] = s;
  __syncthreads();
  for (int off = 128; off > 0; off >>= 1) {
    if (t < off) red[t] += red[t + off];
    __syncthreads();
  }
  if (t == 0) chunk_sums[b] = red[0];
}

__global__ void scan_block_kernel(const int* __restrict__ counts,
                                  const int* __restrict__ chunk_sums,
                                  int* __restrict__ offsets,
                                  int* __restrict__ cursor, int N, int E) {
  __shared__ int part[256];
  __shared__ int chunk_base_sh;
  int b = blockIdx.x, t = threadIdx.x;
  if (t < 64) {
    int v = (t < b) ? chunk_sums[t] : 0;
#pragma unroll
    for (int off = 32; off > 0; off >>= 1) v += __shfl_down(v, off);
    if (t == 0) chunk_base_sh = v;
  }
  int base = b * 1024 + t * 4;
  int v[4];
#pragma unroll
  for (int j = 0; j < 4; ++j) v[j] = (base + j < N) ? counts[base + j] : 0;
  int local = v[0] + v[1] + v[2] + v[3];
  part[t] = local;
  __syncthreads();
  for (int off = 1; off < 256; off <<= 1) {
    int x = 0;
    if (t >= off) x = part[t - off];
    __syncthreads();
    if (t >= off) part[t] += x;
    __syncthreads();
  }
  int run = chunk_base_sh + (part[t] - local);
#pragma unroll
  for (int j = 0; j < 4; ++j) {
    if (base + j < N) {
      offsets[base + j] = run;
      cursor[base + j] = run;
      run += v[j];
    }
  }
  if (b == 0 && t == 0) offsets[N] = E;
}

// ---------------------------------------------------------------------------
// Fused edge geometry + CSR scatter into 64B EdgeRec records.
// ---------------------------------------------------------------------------
__global__ void edge_geom_kernel(const float* __restrict__ pos,
                                 const int* __restrict__ src,
                                 const int* __restrict__ tgt,
                                 int* __restrict__ cursor,
                                 EdgeRec* __restrict__ recs, int E) {
  int e = blockIdx.x * 256 + threadIdx.x;
  if (e >= E) return;
  const int sn = src[e];
  const int tn = tgt[e];
  const float rx = pos[tn * 3 + 0] - pos[sn * 3 + 0];
  const float ry = pos[tn * 3 + 1] - pos[sn * 3 + 1];
  const float rz = pos[tn * 3 + 2] - pos[sn * 3 + 2];
  const float dist = sqrtf(rx * rx + ry * ry + rz * rz);
  const float inv = 1.0f / dist;

  const float ang = dist * (PI_F / CUT_OFF_F);
  float s1, c1;
  sincosf(ang, &s1, &c1);
  float sk = s1, ck = c1;
  float rb[NUM_RBF];
  rb[0] = s1 * inv;
#pragma unroll
  for (int r = 1; r < NUM_RBF; ++r) {
    float sn2 = sk * c1 + ck * s1;
    ck = ck * c1 - sk * s1;
    sk = sn2;
    rb[r] = sk * inv;
  }

  const int p = atomicAdd(&cursor[tn], 1);
  uint_t us[10];
#pragma unroll
  for (int q = 0; q < 10; ++q) us[q] = pack2h(rb[2 * q], rb[2 * q + 1]);
  uint_t* o = reinterpret_cast<uint_t*>(&recs[p]);
  *reinterpret_cast<uint4*>(o) = make_uint4(us[0], us[1], us[2], us[3]);
  *reinterpret_cast<uint4*>(o + 4) = make_uint4(us[4], us[5], us[6], us[7]);
  *reinterpret_cast<uint4*>(o + 8) =
      make_uint4(us[8], us[9], (uint_t)sn, __float_as_uint(rx * inv));
  *reinterpret_cast<uint4*>(o + 12) =
      make_uint4(__float_as_uint(ry * inv), __float_as_uint(rz * inv), 0u, 0u);
}

// ---------------------------------------------------------------------------
// Node gather (R12-verified). One wave-uniform 64B record + 3 per-lane
// merged dwords per edge; plain uniform loop, x2 unroll.
// ---------------------------------------------------------------------------
#define NODES_PER_BLOCK 8

__device__ __forceinline__ float cutoff_f(float x) {
  return (x < CUT_OFF_F) ? 0.5f * (1.0f + __cosf(x * (PI_F / CUT_OFF_F))) : 0.f;
}

__global__ __launch_bounds__(128) void node_kernel(
    const uint_t* __restrict__ merged, const EdgeRec* __restrict__ recs,
    const int* __restrict__ offsets, const float* __restrict__ Wr,
    const float* __restrict__ br, float* __restrict__ out, int N) {
  const int d = threadIdx.x;

  h2v wr0h[10], wr1h[10], wr2h[10];
#pragma unroll
  for (int q = 0; q < 10; ++q) {
    h2v w;
    w.x = (_Float16)Wr[(2 * q) * 384 + 3 * d + 0];
    w.y = (_Float16)Wr[(2 * q + 1) * 384 + 3 * d + 0];
    wr0h[q] = w;
    w.x = (_Float16)Wr[(2 * q) * 384 + 3 * d + 1];
    w.y = (_Float16)Wr[(2 * q + 1) * 384 + 3 * d + 1];
    wr1h[q] = w;
    w.x = (_Float16)Wr[(2 * q) * 384 + 3 * d + 2];
    w.y = (_Float16)Wr[(2 * q + 1) * 384 + 3 * d + 2];
    wr2h[q] = w;
  }
  const float br0 = br[3 * d + 0];
  const float br1 = br[3 * d + 1];
  const float br2 = br[3 * d + 2];

  for (int nn = 0; nn < NODES_PER_BLOCK; ++nn) {
    const int n = blockIdx.x * NODES_PER_BLOCK + nn;
    if (n >= N) break;

    const int start = offsets[n];
    const int end = offsets[n + 1];

    float accs = 0.f, av0 = 0.f, av1 = 0.f, av2 = 0.f;

    int i = start;
    for (; i + 2 <= end; i += 2) {
      const int i0 = __builtin_amdgcn_readfirstlane(i);
      const EdgeRec& eA = recs[i0];
      const EdgeRec& eB = recs[i0 + 1];
      const int snA = (int)eA.src;
      const int snB = (int)eB.src;
      const uint_t* mpA = merged + ((size_t)snA * 128 + d) * 3;
      const uint_t* mpB = merged + ((size_t)snB * 128 + d) * 3;
      const uint_t suA0 = mpA[0], suA1 = mpA[1], suA2 = mpA[2];
      const uint_t suB0 = mpB[0], suB1 = mpB[1], suB2 = mpB[2];

      {
        float f0 = br0, f1 = br1, f2 = br2;
#pragma unroll
        for (int q = 0; q < 10; ++q) {
          h2v r = u2h2(eA.rb[q]);
          f0 = fdot2f(r, wr0h[q], f0);
          f1 = fdot2f(r, wr1h[q], f1);
          f2 = fdot2f(r, wr2h[q], f2);
        }
        f0 = cutoff_f(f0);
        f1 = cutoff_f(f1);
        f2 = cutoff_f(f2);
        const float m0 = h2f_lo(suA0) * f0;
        const float m1 = h2f_hi(suA0) * f1;
        const float m2 = h2f_lo(suA1) * f2;
        accs += m0;
        av0 += m2 * eA.dx + m1 * h2f_hi(suA1);
        av1 += m2 * eA.dy + m1 * h2f_lo(suA2);
        av2 += m2 * eA.dz + m1 * h2f_hi(suA2);
      }
      {
        float f0 = br0, f1 = br1, f2 = br2;
#pragma unroll
        for (int q = 0; q < 10; ++q) {
          h2v r = u2h2(eB.rb[q]);
          f0 = fdot2f(r, wr0h[q], f0);
          f1 = fdot2f(r, wr1h[q], f1);
          f2 = fdot2f(r, wr2h[q], f2);
        }
        f0 = cutoff_f(f0);
        f1 = cutoff_f(f1);
        f2 = cutoff_f(f2);
        const float m0 = h2f_lo(suB0) * f0;
        const float m1 = h2f_hi(suB0) * f1;
        const float m2 = h2f_lo(suB1) * f2;
        accs += m0;
        av0 += m2 * eB.dx + m1 * h2f_hi(suB1);
        av1 += m2 * eB.dy + m1 * h2f_lo(suB2);
        av2 += m2 * eB.dz + m1 * h2f_hi(suB2);
      }
    }
    if (i < end) {
      const int i0 = __builtin_amdgcn_readfirstlane(i);
      const EdgeRec& eA = recs[i0];
      const int snA = (int)eA.src;
      const uint_t* mpA = merged + ((size_t)snA * 128 + d) * 3;
      const uint_t suA0 = mpA[0], suA1 = mpA[1], suA2 = mpA[2];
      float f0 = br0, f1 = br1, f2 = br2;
#pragma unroll
      for (int q = 0; q < 10; ++q) {
        h2v r = u2h2(eA.rb[q]);
        f0 = fdot2f(r, wr0h[q], f0);
        f1 = fdot2f(r, wr1h[q], f1);
        f2 = fdot2f(r, wr2h[q], f2);
      }
      f0 = cutoff_f(f0);
      f1 = cutoff_f(f1);
      f2 = cutoff_f(f2);
      const float m0 = h2f_lo(suA0) * f0;
      const float m1 = h2f_hi(suA0) * f1;
      const float m2 = h2f_lo(suA1) * f2;
      accs += m0;
      av0 += m2 * eA.dx + m1 * h2f_hi(suA1);
      av1 += m2 * eA.dy + m1 * h2f_lo(suA2);
      av2 += m2 * eA.dz + m1 * h2f_hi(suA2);
    }

    out[(size_t)n * 384 + 3 * d + 0] = av0;
    out[(size_t)n * 384 + 3 * d + 1] = av1;
    out[(size_t)n * 384 + 3 * d + 2] = av2;
    out[(size_t)N * 384 + (size_t)n * 128 + d] = accs;
  }
}

// ---------------------------------------------------------------------------
extern "C" void kernel_launch(void* const* d_in, const int* in_sizes, int n_in,
                              void* d_out, int out_size, void* d_ws,
                              size_t ws_size, hipStream_t stream) {
  const float* vf  = (const float*)d_in[0];   // [N,128,3]
  const float* X   = (const float*)d_in[1];   // [N,128]
  const float* pos = (const float*)d_in[2];   // [N,3]
  const int* ei    = (const int*)d_in[3];     // [2,E]
  const float* W1  = (const float*)d_in[4];
  const float* b1  = (const float*)d_in[5];
  const float* W2  = (const float*)d_in[6];
  const float* b2  = (const float*)d_in[7];
  const float* Wr  = (const float*)d_in[8];
  const float* br  = (const float*)d_in[9];

  const int N = in_sizes[1] / D_DIM;
  const int E = in_sizes[3] / 2;
  const int* srcI = ei;
  const int* tgtI = ei + E;
  float* out = (float*)d_out;

  // workspace layout (16B-aligned chunks first)
  char* w = (char*)d_ws;
  EdgeRec* recs  = (EdgeRec*)w; w += (size_t)E * sizeof(EdgeRec);
  uint_t* merged = (uint_t*)w;  w += (size_t)N * 128 * 3 * sizeof(uint_t);
  int* counts    = (int*)w;     w += (size_t)N * sizeof(int);
  int* offsets   = (int*)w;     w += (size_t)(N + 1) * sizeof(int);
  int* cursor    = (int*)w;     w += (size_t)N * sizeof(int);
  int* chunks    = (int*)w;     w += 64 * sizeof(int);

  const int nch = (N + 1023) / 1024;  // 49 for N=50000 (<= 64 required)

  proj_kernel<<<(N + 63) / 64, 256, 0, stream>>>(X, W1, b1, W2, b2, vf, merged,
                                                 counts, N);
  hist_kernel<<<(E + 255) / 256, 256, 0, stream>>>(tgtI, counts, E);
  chunk_sum_kernel<<<nch, 256, 0, stream>>>(counts, chunks, N);
  scan_block_kernel<<<nch, 256, 0, stream>>>(counts, chunks, offsets, cursor,
                                             N, E);
  edge_geom_kernel<<<(E + 255) / 256, 256, 0, stream>>>(pos, srcI, tgtI, cursor,
                                                        recs, E);
  node_kernel<<<(N + NODES_PER_BLOCK - 1) / NODES_PER_BLOCK, 128, 0, stream>>>(
      merged, recs, offsets, Wr, br, out, N);
}

// Round 14
// 274.074 us; speedup vs baseline: 1.2904x; 1.0276x over previous
//
#include <hip/hip_runtime.h>
#include <hip/hip_fp16.h>
#include <math.h>
#include <stddef.h>

#define D_DIM 128
#define NUM_RBF 20
typedef unsigned short ushort_t;
typedef unsigned int uint_t;
typedef _Float16 h2v __attribute__((ext_vector_type(2)));
typedef _Float16 half8_t __attribute__((ext_vector_type(8)));
typedef float float4_t __attribute__((ext_vector_type(4)));
constexpr float PI_F = 3.14159265358979323846f;
constexpr float CUT_OFF_F = 5.0f;
constexpr float SILU_SCALE_F = 1.0f / 0.6f;

__device__ __forceinline__ uint_t pack2h(float a, float b) {
  __half2 h2 = __floats2half2_rn(a, b);
  return *reinterpret_cast<uint_t*>(&h2);
}
__device__ __forceinline__ float h2f(ushort_t u) {
  __half h = __ushort_as_half(u);
  return __half2float(h);
}
__device__ __forceinline__ float h2f_lo(uint_t u) { return h2f((ushort_t)(u & 0xffffu)); }
__device__ __forceinline__ float h2f_hi(uint_t u) { return h2f((ushort_t)(u >> 16)); }
__device__ __forceinline__ h2v u2h2(uint_t u) {
  h2v r;
  __builtin_memcpy(&r, &u, 4);
  return r;
}

#if defined(__has_builtin)
#if __has_builtin(__builtin_amdgcn_fdot2)
#define HAVE_FDOT2 1
#endif
#endif

__device__ __forceinline__ float fdot2f(h2v a, h2v b, float c) {
#ifdef HAVE_FDOT2
  return __builtin_amdgcn_fdot2(a, b, c, false);
#else
  return c + (float)a.x * (float)b.x + (float)a.y * (float)b.y;
#endif
}

// 64B per-edge record: all wave-uniform data in one scalar-loadable block.
struct __align__(16) EdgeRec {
  uint_t rb[10];   // rbf packed fp16x2
  uint_t src;      // source node
  float dx, dy, dz;
  uint_t pad[2];
};

// ---------------------------------------------------------------------------
// MFMA node projection + merged-buffer build + counts zeroing (R13-verified).
// ---------------------------------------------------------------------------
__device__ __forceinline__ void stage_wt(const float* __restrict__ W,
                                         _Float16* __restrict__ Wt, int t,
                                         int f4stride, int f4base) {
  const float4* Wv = reinterpret_cast<const float4*>(W);
#pragma unroll
  for (int i = 0; i < 8; ++i) {
    int pid = t + i * 256;            // 0..2047: 64 k-pairs x 32 n-float4s
    int k = (pid >> 5) * 2;
    int nf = pid & 31;
    float4 a = Wv[(size_t)k * f4stride + f4base + nf];
    float4 b = Wv[(size_t)(k + 1) * f4stride + f4base + nf];
    const float av[4] = {a.x, a.y, a.z, a.w};
    const float bv[4] = {b.x, b.y, b.z, b.w};
    const int n0 = nf * 4;
#pragma unroll
    for (int j = 0; j < 4; ++j)
      *reinterpret_cast<uint_t*>(&Wt[(n0 + j) * 136 + k]) =
          pack2h(av[j], bv[j]);
  }
}

__global__ __launch_bounds__(256) void proj_kernel(
    const float* __restrict__ X, const float* __restrict__ W1,
    const float* __restrict__ b1, const float* __restrict__ W2,
    const float* __restrict__ b2, const float* __restrict__ vf,
    uint_t* __restrict__ merged, int* __restrict__ counts, int N) {
  __shared__ alignas(16) _Float16 smem[26112];  // Xs[64*136] + Wt[128*136]
  _Float16* Xs = smem;
  _Float16* Wt = smem + 8704;

  const int t = threadIdx.x;
  const int w = t >> 6;        // wave 0..3
  const int l = t & 63;        // lane
  const int nb = blockIdx.x * 64;

  // ---- fold-in: zero the CSR counts array ----
  {
    int z = blockIdx.x * 256 + t;
    if (z < N) counts[z] = 0;
  }

  // ---- stage X tile: [64][128] fp32 -> Xs[64][136] fp16 ----
  {
    const float4* Xv = reinterpret_cast<const float4*>(X);
#pragma unroll
    for (int i = 0; i < 8; ++i) {
      int g = t + i * 256;            // 0..2047
      int row = g >> 5, k0 = (g & 31) * 4;
      int node = nb + row;
      float4 v = (node < N) ? Xv[(size_t)nb * 32 + g]
                            : make_float4(0.f, 0.f, 0.f, 0.f);
      uint_t* dst = reinterpret_cast<uint_t*>(&Xs[row * 136 + k0]);
      dst[0] = pack2h(v.x, v.y);
      dst[1] = pack2h(v.z, v.w);
    }
  }
  stage_wt(W1, Wt, t, 32, 0);
  __syncthreads();

  const int arow = w * 16 + (l & 15);
  const int koff = (l >> 4) * 8;
  const int bcol = l & 15;

  // ---- phase 1: H = X @ W1 ----
  half8_t af[4];
#pragma unroll
  for (int s = 0; s < 4; ++s)
    af[s] = *reinterpret_cast<const half8_t*>(&Xs[arow * 136 + s * 32 + koff]);

  float4_t acc[8];
#pragma unroll
  for (int c = 0; c < 8; ++c) {
    float4_t a = {0.f, 0.f, 0.f, 0.f};
#pragma unroll
    for (int s = 0; s < 4; ++s) {
      half8_t bf = *reinterpret_cast<const half8_t*>(
          &Wt[(c * 16 + bcol) * 136 + s * 32 + koff]);
      a = __builtin_amdgcn_mfma_f32_16x16x32_f16(af[s], bf, a, 0, 0, 0);
    }
    acc[c] = a;
  }

  __syncthreads();  // all Xs/Wt reads done before overwrite

  // ---- bias + scaled-silu -> H (fp16) into Xs; stage W2 chunk 0 ----
#pragma unroll
  for (int c = 0; c < 8; ++c) {
    const int col = c * 16 + bcol;
    const float bv = b1[col];
#pragma unroll
    for (int r = 0; r < 4; ++r) {
      const int row = w * 16 + (l >> 4) * 4 + r;
      float hv = acc[c][r] + bv;
      hv = hv * SILU_SCALE_F / (1.0f + expf(-hv));
      Xs[row * 136 + col] = (_Float16)hv;
    }
  }
  stage_wt(W2, Wt, t, 96, 0);
  __syncthreads();

  // ---- phase 2: S = H @ W2 + b2, 3 col-chunks of 128; results in regs ----
  half8_t ha[4];
#pragma unroll
  for (int s = 0; s < 4; ++s)
    ha[s] = *reinterpret_cast<const half8_t*>(&Xs[arow * 136 + s * 32 + koff]);

  uint_t pk[3][8][2];   // packed fp16 results; fully static indexing
#pragma unroll
  for (int cn = 0; cn < 3; ++cn) {
    if (cn > 0) {
      __syncthreads();                // prev chunk's Wt reads done
      stage_wt(W2, Wt, t, 96, cn * 32);
      __syncthreads();
    }
#pragma unroll
    for (int c = 0; c < 8; ++c) {
      float4_t a = {0.f, 0.f, 0.f, 0.f};
#pragma unroll
      for (int s = 0; s < 4; ++s) {
        half8_t bf = *reinterpret_cast<const half8_t*>(
            &Wt[(c * 16 + bcol) * 136 + s * 32 + koff]);
        a = __builtin_amdgcn_mfma_f32_16x16x32_f16(ha[s], bf, a, 0, 0, 0);
      }
      const float bv = b2[cn * 128 + c * 16 + bcol];
      pk[cn][c][0] = pack2h(a[0] + bv, a[1] + bv);
      pk[cn][c][1] = pack2h(a[2] + bv, a[3] + bv);
    }
  }

  // ---- bounce S to LDS natural [64][392] ----
  __syncthreads();                    // all Wt reads done; smem reusable
  ushort_t* sh = reinterpret_cast<ushort_t*>(smem);
  {
    const int rbase = w * 16 + (l >> 4) * 4;
#pragma unroll
    for (int cn = 0; cn < 3; ++cn)
#pragma unroll
      for (int c = 0; c < 8; ++c) {
        const int gcol = cn * 128 + c * 16 + bcol;
        sh[(rbase + 0) * 392 + gcol] = (ushort_t)(pk[cn][c][0] & 0xffffu);
        sh[(rbase + 1) * 392 + gcol] = (ushort_t)(pk[cn][c][0] >> 16);
        sh[(rbase + 2) * 392 + gcol] = (ushort_t)(pk[cn][c][1] & 0xffffu);
        sh[(rbase + 3) * 392 + gcol] = (ushort_t)(pk[cn][c][1] >> 16);
      }
  }
  __syncthreads();

  // ---- merged build, vectorized 4 chans/work-item ----
#pragma unroll
  for (int k = 0; k < 8; ++k) {
    const int P = k * 256 + t;        // 0..2047
    const int ln = P >> 5;            // local node 0..63
    const int cg = (P & 31) * 4;      // chan group base 0,4,..,124
    const int node = nb + ln;
    if (node < N) {
      const ushort_t* sp = &sh[ln * 392 + 3 * cg];
      uint2 sa = *reinterpret_cast<const uint2*>(sp);
      uint2 sb = *reinterpret_cast<const uint2*>(sp + 4);
      uint2 sc = *reinterpret_cast<const uint2*>(sp + 8);
      ushort_t s12[12];
      s12[0] = (ushort_t)(sa.x & 0xffffu);  s12[1] = (ushort_t)(sa.x >> 16);
      s12[2] = (ushort_t)(sa.y & 0xffffu);  s12[3] = (ushort_t)(sa.y >> 16);
      s12[4] = (ushort_t)(sb.x & 0xffffu);  s12[5] = (ushort_t)(sb.x >> 16);
      s12[6] = (ushort_t)(sb.y & 0xffffu);  s12[7] = (ushort_t)(sb.y >> 16);
      s12[8] = (ushort_t)(sc.x & 0xffffu);  s12[9] = (ushort_t)(sc.x >> 16);
      s12[10] = (ushort_t)(sc.y & 0xffffu); s12[11] = (ushort_t)(sc.y >> 16);

      const float4* vp =
          reinterpret_cast<const float4*>(vf + ((size_t)node * 128 + cg) * 3);
      float4 v0 = vp[0], v1 = vp[1], v2 = vp[2];
      float vv[12] = {v0.x, v0.y, v0.z, v0.w, v1.x, v1.y,
                      v1.z, v1.w, v2.x, v2.y, v2.z, v2.w};

      uint_t o[12];
#pragma unroll
      for (int j = 0; j < 4; ++j) {
        o[3 * j + 0] = (uint_t)s12[3 * j] | ((uint_t)s12[3 * j + 1] << 16);
        o[3 * j + 1] =
            (uint_t)s12[3 * j + 2] |
            ((uint_t)__half_as_ushort(__float2half_rn(vv[3 * j])) << 16);
        o[3 * j + 2] = pack2h(vv[3 * j + 1], vv[3 * j + 2]);
      }
      uint_t* mp = merged + ((size_t)node * 128 + cg) * 3;
      *reinterpret_cast<uint4*>(mp) = make_uint4(o[0], o[1], o[2], o[3]);
      *reinterpret_cast<uint4*>(mp + 4) = make_uint4(o[4], o[5], o[6], o[7]);
      *reinterpret_cast<uint4*>(mp + 8) = make_uint4(o[8], o[9], o[10], o[11]);
    }
  }
}

// ---------------------------------------------------------------------------
// CSR build
// ---------------------------------------------------------------------------
__global__ void hist_kernel(const int* __restrict__ tgt, int* __restrict__ counts,
                            int E) {
  int e = blockIdx.x * 256 + threadIdx.x;
  if (e < E) atomicAdd(&counts[tgt[e]], 1);
}

__global__ void chunk_sum_kernel(const int* __restrict__ counts,
                                 int* __restrict__ chunk_sums, int N) {
  __shared__ int red[256];
  int b = blockIdx.x, t = threadIdx.x;
  int base = b * 1024 + t * 4;
  int s = 0;
#pragma unroll
  for (int j = 0; j < 4; ++j) s += (base + j < N) ? counts[base + j] : 0;
  red[t] = s;
  __syncthreads();
  for (int off = 128; off > 0; off >>= 1) {
    if (t < off) red[t] += red[t + off];
    __syncthreads();
  }
  if (t == 0) chunk_sums[b] = red[0];
}

__global__ void scan_block_kernel(const int* __restrict__ counts,
                                  const int* __restrict__ chunk_sums,
                                  int* __restrict__ offsets,
                                  int* __restrict__ cursor, int N, int E) {
  __shared__ int part[256];
  __shared__ int chunk_base_sh;
  int b = blockIdx.x, t = threadIdx.x;
  if (t < 64) {
    int v = (t < b) ? chunk_sums[t] : 0;
#pragma unroll
    for (int off = 32; off > 0; off >>= 1) v += __shfl_down(v, off);
    if (t == 0) chunk_base_sh = v;
  }
  int base = b * 1024 + t * 4;
  int v[4];
#pragma unroll
  for (int j = 0; j < 4; ++j) v[j] = (base + j < N) ? counts[base + j] : 0;
  int local = v[0] + v[1] + v[2] + v[3];
  part[t] = local;
  __syncthreads();
  for (int off = 1; off < 256; off <<= 1) {
    int x = 0;
    if (t >= off) x = part[t - off];
    __syncthreads();
    if (t >= off) part[t] += x;
    __syncthreads();
  }
  int run = chunk_base_sh + (part[t] - local);
#pragma unroll
  for (int j = 0; j < 4; ++j) {
    if (base + j < N) {
      offsets[base + j] = run;
      cursor[base + j] = run;
      run += v[j];
    }
  }
  if (b == 0 && t == 0) offsets[N] = E;
}

// ---------------------------------------------------------------------------
// Fused edge geometry + CSR scatter into 64B EdgeRec records.
// ---------------------------------------------------------------------------
__global__ void edge_geom_kernel(const float* __restrict__ pos,
                                 const int* __restrict__ src,
                                 const int* __restrict__ tgt,
                                 int* __restrict__ cursor,
                                 EdgeRec* __restrict__ recs, int E) {
  int e = blockIdx.x * 256 + threadIdx.x;
  if (e >= E) return;
  const int sn = src[e];
  const int tn = tgt[e];
  const float rx = pos[tn * 3 + 0] - pos[sn * 3 + 0];
  const float ry = pos[tn * 3 + 1] - pos[sn * 3 + 1];
  const float rz = pos[tn * 3 + 2] - pos[sn * 3 + 2];
  const float dist = sqrtf(rx * rx + ry * ry + rz * rz);
  const float inv = 1.0f / dist;

  const float ang = dist * (PI_F / CUT_OFF_F);
  float s1, c1;
  sincosf(ang, &s1, &c1);
  float sk = s1, ck = c1;
  float rb[NUM_RBF];
  rb[0] = s1 * inv;
#pragma unroll
  for (int r = 1; r < NUM_RBF; ++r) {
    float sn2 = sk * c1 + ck * s1;
    ck = ck * c1 - sk * s1;
    sk = sn2;
    rb[r] = sk * inv;
  }

  const int p = atomicAdd(&cursor[tn], 1);
  uint_t us[10];
#pragma unroll
  for (int q = 0; q < 10; ++q) us[q] = pack2h(rb[2 * q], rb[2 * q + 1]);
  uint_t* o = reinterpret_cast<uint_t*>(&recs[p]);
  *reinterpret_cast<uint4*>(o) = make_uint4(us[0], us[1], us[2], us[3]);
  *reinterpret_cast<uint4*>(o + 4) = make_uint4(us[4], us[5], us[6], us[7]);
  *reinterpret_cast<uint4*>(o + 8) =
      make_uint4(us[8], us[9], (uint_t)sn, __float_as_uint(rx * inv));
  *reinterpret_cast<uint4*>(o + 12) =
      make_uint4(__float_as_uint(ry * inv), __float_as_uint(rz * inv), 0u, 0u);
}

// ---------------------------------------------------------------------------
// Node gather. One wave-uniform 64B record + 3 per-lane merged dwords per
// edge. x4 unroll with upfront loads (MLP); cutoff via raw v_cos_f32
// (arg f/10 revolutions in [0,0.5) when live — no range reduction).
// ---------------------------------------------------------------------------
#define NODES_PER_BLOCK 8

__device__ __forceinline__ float cutoff_f(float x) {
#if defined(__has_builtin)
#if __has_builtin(__builtin_amdgcn_cosf)
  float c = __builtin_amdgcn_cosf(x * 0.1f);   // v_cos_f32: revolutions
#else
  float c = __cosf(x * (PI_F / CUT_OFF_F));
#endif
#else
  float c = __cosf(x * (PI_F / CUT_OFF_F));
#endif
  return (x < CUT_OFF_F) ? 0.5f + 0.5f * c : 0.f;
}

__device__ __forceinline__ void edge_body(const EdgeRec& e, uint_t su0,
                                          uint_t su1, uint_t su2,
                                          const h2v* wr0h, const h2v* wr1h,
                                          const h2v* wr2h, float br0, float br1,
                                          float br2, float& accs, float& av0,
                                          float& av1, float& av2) {
  float f0 = br0, f1 = br1, f2 = br2;
#pragma unroll
  for (int q = 0; q < 10; ++q) {
    h2v r = u2h2(e.rb[q]);
    f0 = fdot2f(r, wr0h[q], f0);
    f1 = fdot2f(r, wr1h[q], f1);
    f2 = fdot2f(r, wr2h[q], f2);
  }
  f0 = cutoff_f(f0);
  f1 = cutoff_f(f1);
  f2 = cutoff_f(f2);
  const float m0 = h2f_lo(su0) * f0;
  const float m1 = h2f_hi(su0) * f1;
  const float m2 = h2f_lo(su1) * f2;
  accs += m0;
  av0 += m2 * e.dx + m1 * h2f_hi(su1);
  av1 += m2 * e.dy + m1 * h2f_lo(su2);
  av2 += m2 * e.dz + m1 * h2f_hi(su2);
}

__global__ __launch_bounds__(128) void node_kernel(
    const uint_t* __restrict__ merged, const EdgeRec* __restrict__ recs,
    const int* __restrict__ offsets, const float* __restrict__ Wr,
    const float* __restrict__ br, float* __restrict__ out, int N) {
  const int d = threadIdx.x;
  const int d3 = 3 * d;

  h2v wr0h[10], wr1h[10], wr2h[10];
#pragma unroll
  for (int q = 0; q < 10; ++q) {
    h2v w;
    w.x = (_Float16)Wr[(2 * q) * 384 + d3 + 0];
    w.y = (_Float16)Wr[(2 * q + 1) * 384 + d3 + 0];
    wr0h[q] = w;
    w.x = (_Float16)Wr[(2 * q) * 384 + d3 + 1];
    w.y = (_Float16)Wr[(2 * q + 1) * 384 + d3 + 1];
    wr1h[q] = w;
    w.x = (_Float16)Wr[(2 * q) * 384 + d3 + 2];
    w.y = (_Float16)Wr[(2 * q + 1) * 384 + d3 + 2];
    wr2h[q] = w;
  }
  const float br0 = br[d3 + 0];
  const float br1 = br[d3 + 1];
  const float br2 = br[d3 + 2];

  for (int nn = 0; nn < NODES_PER_BLOCK; ++nn) {
    const int n = blockIdx.x * NODES_PER_BLOCK + nn;
    if (n >= N) break;

    const int start = offsets[n];
    const int end = offsets[n + 1];

    float accs = 0.f, av0 = 0.f, av1 = 0.f, av2 = 0.f;

    int i = start;
    // ---- x4 unrolled: all loads up front, then 4 computes ----
    for (; i + 4 <= end; i += 4) {
      const int i0 = __builtin_amdgcn_readfirstlane(i);
      const EdgeRec& eA = recs[i0];
      const EdgeRec& eB = recs[i0 + 1];
      const EdgeRec& eC = recs[i0 + 2];
      const EdgeRec& eD = recs[i0 + 3];
      const uint_t* mpA = merged + (size_t)eA.src * 384 + d3;
      const uint_t* mpB = merged + (size_t)eB.src * 384 + d3;
      const uint_t* mpC = merged + (size_t)eC.src * 384 + d3;
      const uint_t* mpD = merged + (size_t)eD.src * 384 + d3;
      const uint_t suA0 = mpA[0], suA1 = mpA[1], suA2 = mpA[2];
      const uint_t suB0 = mpB[0], suB1 = mpB[1], suB2 = mpB[2];
      const uint_t suC0 = mpC[0], suC1 = mpC[1], suC2 = mpC[2];
      const uint_t suD0 = mpD[0], suD1 = mpD[1], suD2 = mpD[2];

      edge_body(eA, suA0, suA1, suA2, wr0h, wr1h, wr2h, br0, br1, br2, accs,
                av0, av1, av2);
      edge_body(eB, suB0, suB1, suB2, wr0h, wr1h, wr2h, br0, br1, br2, accs,
                av0, av1, av2);
      edge_body(eC, suC0, suC1, suC2, wr0h, wr1h, wr2h, br0, br1, br2, accs,
                av0, av1, av2);
      edge_body(eD, suD0, suD1, suD2, wr0h, wr1h, wr2h, br0, br1, br2, accs,
                av0, av1, av2);
    }
    for (; i < end; ++i) {
      const int i0 = __builtin_amdgcn_readfirstlane(i);
      const EdgeRec& eA = recs[i0];
      const uint_t* mpA = merged + (size_t)eA.src * 384 + d3;
      const uint_t suA0 = mpA[0], suA1 = mpA[1], suA2 = mpA[2];
      edge_body(eA, suA0, suA1, suA2, wr0h, wr1h, wr2h, br0, br1, br2, accs,
                av0, av1, av2);
    }

    out[(size_t)n * 384 + d3 + 0] = av0;
    out[(size_t)n * 384 + d3 + 1] = av1;
    out[(size_t)n * 384 + d3 + 2] = av2;
    out[(size_t)N * 384 + (size_t)n * 128 + d] = accs;
  }
}

// ---------------------------------------------------------------------------
extern "C" void kernel_launch(void* const* d_in, const int* in_sizes, int n_in,
                              void* d_out, int out_size, void* d_ws,
                              size_t ws_size, hipStream_t stream) {
  const float* vf  = (const float*)d_in[0];   // [N,128,3]
  const float* X   = (const float*)d_in[1];   // [N,128]
  const float* pos = (const float*)d_in[2];   // [N,3]
  const int* ei    = (const int*)d_in[3];     // [2,E]
  const float* W1  = (const float*)d_in[4];
  const float* b1  = (const float*)d_in[5];
  const float* W2  = (const float*)d_in[6];
  const float* b2  = (const float*)d_in[7];
  const float* Wr  = (const float*)d_in[8];
  const float* br  = (const float*)d_in[9];

  const int N = in_sizes[1] / D_DIM;
  const int E = in_sizes[3] / 2;
  const int* srcI = ei;
  const int* tgtI = ei + E;
  float* out = (float*)d_out;

  // workspace layout (16B-aligned chunks first)
  char* w = (char*)d_ws;
  EdgeRec* recs  = (EdgeRec*)w; w += (size_t)E * sizeof(EdgeRec);
  uint_t* merged = (uint_t*)w;  w += (size_t)N * 128 * 3 * sizeof(uint_t);
  int* counts    = (int*)w;     w += (size_t)N * sizeof(int);
  int* offsets   = (int*)w;     w += (size_t)(N + 1) * sizeof(int);
  int* cursor    = (int*)w;     w += (size_t)N * sizeof(int);
  int* chunks    = (int*)w;     w += 64 * sizeof(int);

  const int nch = (N + 1023) / 1024;  // 49 for N=50000 (<= 64 required)

  proj_kernel<<<(N + 63) / 64, 256, 0, stream>>>(X, W1, b1, W2, b2, vf, merged,
                                                 counts, N);
  hist_kernel<<<(E + 255) / 256, 256, 0, stream>>>(tgtI, counts, E);
  chunk_sum_kernel<<<nch, 256, 0, stream>>>(counts, chunks, N);
  scan_block_kernel<<<nch, 256, 0, stream>>>(counts, chunks, offsets, cursor,
                                             N, E);
  edge_geom_kernel<<<(E + 255) / 256, 256, 0, stream>>>(pos, srcI, tgtI, cursor,
                                                        recs, E);
  node_kernel<<<(N + NODES_PER_BLOCK - 1) / NODES_PER_BLOCK, 128, 0, stream>>>(
      merged, recs, offsets, Wr, br, out, N);
}